// Round 1
// baseline (772.202 us; speedup 1.0000x reference)
//
#include <hip/hip_runtime.h>
#include <hip/hip_bf16.h>
#include <math.h>

#define NN 2048
#define DD 256
#define KK 20
#define HH 4

struct GatherPtrs { const float* p[5]; };

__device__ inline float wsum(float v){
  #pragma unroll
  for (int o=32;o;o>>=1) v += __shfl_xor(v,o);
  return v;
}
__device__ inline float wmax(float v){
  #pragma unroll
  for (int o=32;o;o>>=1) v = fmaxf(v,__shfl_xor(v,o));
  return v;
}

// ---------------- Kernel A: wa[h,d] = sum_e W[h,d,e]*a[h,e] ----------------
__global__ void wa_kernel(const float* __restrict__ W, const float* __restrict__ a,
                          float* __restrict__ wa){
  int t = blockIdx.x*blockDim.x + threadIdx.x;   // 0..H*D-1
  int h = t >> 8, d = t & 255;
  const float* wrow = W + (size_t)(h*DD + d)*DD;
  const float* av = a + h*DD;
  float acc = 0.f;
  #pragma unroll 4
  for (int e=0;e<DD;e++) acc += wrow[e]*av[e];
  wa[t] = acc;
}

// ------------- Kernel B: fused gather-max + instance attention -------------
// one block per node n; 256 threads (4 waves)
template<int P>
__launch_bounds__(256)
__global__ void inst_attn_kernel(const float* __restrict__ Xt,
                                 GatherPtrs xs,
                                 const int* __restrict__ idx,
                                 const float* __restrict__ wa,   // [H][D]
                                 float* __restrict__ ctx){       // [N][H*D]
  __shared__ float inst_s[KK][DD];      // 20 KB
  __shared__ float wa_s[HH*DD];         // 4 KB
  __shared__ float e_s[HH][KK];
  __shared__ float alpha_s[HH][KK];
  __shared__ float s_s[HH];

  const int n = blockIdx.x;
  const int t = threadIdx.x;
  const int w = t >> 6;     // wave id 0..3
  const int l = t & 63;     // lane

  ((float4*)wa_s)[t] = ((const float4*)wa)[t];   // 1024 floats
  __syncthreads();

  // s[h] = Xt[n]·wa[h], one head per wave
  {
    float4 xv = ((const float4*)(Xt + (size_t)n*DD))[l];
    float4 wv = ((const float4*)(wa_s + w*DD))[l];
    float p = xv.x*wv.x + xv.y*wv.y + xv.z*wv.z + xv.w*wv.w;
    p = wsum(p);
    if (l==0) s_s[w] = p;
  }
  __syncthreads();

  for (int k = w; k < KK; k += 4) {
    const int* ib = idx + ((size_t)n*KK + k)*P;
    float4 v;
    {
      int id = ib[0];
      v = ((const float4*)(xs.p[0] + (size_t)id*DD))[l];
    }
    #pragma unroll
    for (int p=1;p<P;p++){
      int id = ib[p];
      float4 u = ((const float4*)(xs.p[p] + (size_t)id*DD))[l];
      v.x = fmaxf(v.x,u.x); v.y = fmaxf(v.y,u.y);
      v.z = fmaxf(v.z,u.z); v.w = fmaxf(v.w,u.w);
    }
    ((float4*)(inst_s[k]))[l] = v;
    #pragma unroll
    for (int h=0;h<HH;h++){
      float4 wv = ((const float4*)(wa_s + h*DD))[l];
      float pr = v.x*wv.x + v.y*wv.y + v.z*wv.z + v.w*wv.w;
      pr = wsum(pr);
      if (l==0){
        float logit = pr + s_s[h];
        e_s[h][k] = (logit > 0.f) ? logit : 0.2f*logit;
      }
    }
  }
  __syncthreads();

  // softmax over K per head (wave w handles head w)
  {
    int h = w;
    float x = (l < KK) ? e_s[h][l] : -INFINITY;
    float mx = wmax(x);
    float pv = (l < KK) ? expf(x - mx) : 0.f;
    float sm = wsum(pv);
    if (l < KK) alpha_s[h][l] = pv / sm;
  }
  __syncthreads();

  // ctx[h] = sum_k alpha[h,k] * inst[k]; thread t owns column d=t
  float c0=0,c1=0,c2=0,c3=0;
  #pragma unroll
  for (int k=0;k<KK;k++){
    float iv = inst_s[k][t];
    c0 += alpha_s[0][k]*iv;
    c1 += alpha_s[1][k]*iv;
    c2 += alpha_s[2][k]*iv;
    c3 += alpha_s[3][k]*iv;
  }
  float* cb = ctx + (size_t)n*(HH*DD);
  cb[0*DD + t] = c0;
  cb[1*DD + t] = c1;
  cb[2*DD + t] = c2;
  cb[3*DD + t] = c3;
}

// ---------- Kernel C: Hmp = (1/H) * ctx[N][1024] @ Wflat[1024][256] ----------
// 8 rows per block; 256 threads: col-group cg=t&63 (4 cols), row-sub r0=t>>6 (rows r0, r0+4)
__launch_bounds__(256)
__global__ void ctxproj_kernel(const float* __restrict__ ctx,
                               const float* __restrict__ W,     // [1024][256]
                               float* __restrict__ out){        // [N][256]
  __shared__ float a_s[8][1024];    // 32 KB
  const int t = threadIdx.x;
  const int n0 = blockIdx.x*8;
  const float4* src = (const float4*)(ctx + (size_t)n0*1024);
  float4* dst = (float4*)&a_s[0][0];
  #pragma unroll
  for (int i=0;i<8;i++) dst[t + i*256] = src[t + i*256];
  __syncthreads();
  const int cg = t & 63;
  const int r0 = t >> 6;
  float4 acc0 = {0,0,0,0}, acc1 = {0,0,0,0};
  const float4* B4 = (const float4*)W;
  #pragma unroll 4
  for (int kk=0; kk<1024; kk++){
    float4 b = B4[kk*64 + cg];
    float a0 = a_s[r0][kk];
    float a1 = a_s[r0+4][kk];
    acc0.x += a0*b.x; acc0.y += a0*b.y; acc0.z += a0*b.z; acc0.w += a0*b.w;
    acc1.x += a1*b.x; acc1.y += a1*b.y; acc1.z += a1*b.z; acc1.w += a1*b.w;
  }
  float4* o0 = (float4*)(out + (size_t)(n0+r0)*DD);
  float4* o1 = (float4*)(out + (size_t)(n0+r0+4)*DD);
  o0[cg] = make_float4(acc0.x*0.25f, acc0.y*0.25f, acc0.z*0.25f, acc0.w*0.25f);
  o1[cg] = make_float4(acc1.x*0.25f, acc1.y*0.25f, acc1.z*0.25f, acc1.w*0.25f);
}

// ------- Kernel E: sem_sum[p,e] += sum_n tanh(H_p[n]·Wm[:,e] + bm[e]) -------
// grid (N/16, P); 16 rows per block; thread owns column e=t
__launch_bounds__(256)
__global__ void sem_kernel(const float* __restrict__ Hbase,   // [P][N][D]
                           const float* __restrict__ Wm,      // [D][D]
                           const float* __restrict__ bm,
                           float* __restrict__ sem_sum){      // [P][D]
  const int p = blockIdx.y;
  const int n0 = blockIdx.x * 16;
  const float* Hp = Hbase + (size_t)p*NN*DD + (size_t)n0*DD;
  __shared__ float h_s[16][DD];   // 16 KB
  const int t = threadIdx.x;
  const float4* src = (const float4*)Hp;
  float4* dst = (float4*)&h_s[0][0];
  #pragma unroll
  for (int i=0;i<4;i++) dst[t + i*256] = src[t + i*256];
  __syncthreads();
  float dot[16];
  #pragma unroll
  for (int r=0;r<16;r++) dot[r]=0.f;
  for (int d=0; d<DD; d++){
    float wv = Wm[(size_t)d*DD + t];
    #pragma unroll
    for (int r=0;r<16;r++) dot[r] += h_s[r][d]*wv;
  }
  float b = bm[t];
  float acc = 0.f;
  #pragma unroll
  for (int r=0;r<16;r++) acc += tanhf(dot[r]+b);
  atomicAdd(&sem_sum[p*DD + t], acc);
}

// ---------------- Kernel F: beta softmax per node type ----------------
struct TypeInfo {
  const float* qm;
  float* sem;       // [P][D] sums
  int P;
  int beta_off;     // offset into beta tail of d_out
};
__global__ void beta_kernel(TypeInfo ti0, TypeInfo ti1, TypeInfo ti2,
                            float* __restrict__ out_beta, float* __restrict__ beta_ws){
  TypeInfo ti = (blockIdx.x==0) ? ti0 : (blockIdx.x==1) ? ti1 : ti2;
  const int t = threadIdx.x;
  __shared__ float red[4];
  __shared__ float logits[3];
  float q = ti.qm[t];
  for (int p=0;p<ti.P;p++){
    float sm = ti.sem[p*DD + t] * (1.0f/NN);
    float v = tanhf(sm)*q;
    v = wsum(v);
    if ((t&63)==0) red[t>>6] = v;
    __syncthreads();
    if (t==0) logits[p] = red[0]+red[1]+red[2]+red[3];
    __syncthreads();
  }
  if (t==0){
    float mx = -INFINITY;
    for (int p=0;p<ti.P;p++) mx = fmaxf(mx, logits[p]);
    float s = 0.f, e[3];
    for (int p=0;p<ti.P;p++){ e[p] = expf(logits[p]-mx); s += e[p]; }
    for (int p=0;p<ti.P;p++){
      float b = e[p]/s;
      out_beta[ti.beta_off + p] = b;
      beta_ws[blockIdx.x*3 + p] = b;
    }
  }
}

// ---------------- Kernel G: out[n,d] = sum_p beta[p]*H_p[n,d] ----------------
__global__ void combine_kernel(const float* __restrict__ Hmp,   // [6][N][D]
                               const float* __restrict__ beta_ws,
                               float* __restrict__ out){
  int type = blockIdx.y;
  int start = (type==0) ? 0 : (type==1) ? 2 : 5;
  int P = (type==0) ? 2 : (type==1) ? 3 : 1;
  size_t i = (size_t)blockIdx.x*blockDim.x + threadIdx.x;   // < N*D
  const float* base = Hmp + (size_t)start*NN*DD;
  float acc = 0.f;
  for (int p=0;p<P;p++) acc += beta_ws[type*3+p]*base[(size_t)p*NN*DD + i];
  out[(size_t)type*NN*DD + i] = acc;
}

extern "C" void kernel_launch(void* const* d_in, const int* in_sizes, int n_in,
                              void* d_out, int out_size, void* d_ws, size_t ws_size,
                              hipStream_t stream) {
  const float* X_drug = (const float*)d_in[0];
  const float* X_dis  = (const float*)d_in[1];
  const float* X_gene = (const float*)d_in[2];
  const int* idx_[6] = { (const int*)d_in[3], (const int*)d_in[4], (const int*)d_in[5],
                         (const int*)d_in[6], (const int*)d_in[7], (const int*)d_in[8] };
  const float* W_[6]; const float* a_[6];
  for (int m=0;m<6;m++){ W_[m] = (const float*)d_in[9+2*m]; a_[m] = (const float*)d_in[10+2*m]; }
  const float* Wm_[3]; const float* bm_[3]; const float* qm_[3];
  for (int tt=0;tt<3;tt++){
    Wm_[tt] = (const float*)d_in[21+3*tt];
    bm_[tt] = (const float*)d_in[22+3*tt];
    qm_[tt] = (const float*)d_in[23+3*tt];
  }

  const int P_[6] = {3,5,3,3,4,5};
  const float* Xt_[6] = {X_drug, X_drug, X_dis, X_dis, X_dis, X_gene};
  GatherPtrs gp[6];
  gp[0] = GatherPtrs{{X_drug, X_dis, X_drug, nullptr, nullptr}};           // rdr
  gp[1] = GatherPtrs{{X_drug, X_dis, X_gene, X_dis, X_drug}};              // rdgdr
  gp[2] = GatherPtrs{{X_dis, X_gene, X_dis, nullptr, nullptr}};            // dgd
  gp[3] = GatherPtrs{{X_dis, X_drug, X_dis, nullptr, nullptr}};            // drd
  gp[4] = GatherPtrs{{X_dis, X_drug, X_drug, X_dis, nullptr}};             // drrd
  gp[5] = GatherPtrs{{X_gene, X_dis, X_drug, X_dis, X_gene}};              // gdrdg

  float* ws = (float*)d_ws;
  float* wa_all  = ws;                           // 6*1024
  float* ctx     = wa_all + 6*1024;              // 2,097,152
  float* Hmp     = ctx + (size_t)NN*HH*DD;       // 6*524,288
  float* sem_sum = Hmp + (size_t)6*NN*DD;        // 6*256
  float* beta_ws = sem_sum + 6*DD;               // 9

  hipMemsetAsync(sem_sum, 0, 6*DD*sizeof(float), stream);

  for (int m=0;m<6;m++)
    wa_kernel<<<dim3(4),dim3(256),0,stream>>>(W_[m], a_[m], wa_all + m*HH*DD);

  for (int m=0;m<6;m++){
    switch (P_[m]){
      case 3: inst_attn_kernel<3><<<dim3(NN),dim3(256),0,stream>>>(Xt_[m], gp[m], idx_[m], wa_all+m*HH*DD, ctx); break;
      case 4: inst_attn_kernel<4><<<dim3(NN),dim3(256),0,stream>>>(Xt_[m], gp[m], idx_[m], wa_all+m*HH*DD, ctx); break;
      case 5: inst_attn_kernel<5><<<dim3(NN),dim3(256),0,stream>>>(Xt_[m], gp[m], idx_[m], wa_all+m*HH*DD, ctx); break;
    }
    ctxproj_kernel<<<dim3(NN/8),dim3(256),0,stream>>>(ctx, W_[m], Hmp + (size_t)m*NN*DD);
  }

  sem_kernel<<<dim3(NN/16,2),dim3(256),0,stream>>>(Hmp,                    Wm_[0], bm_[0], sem_sum + 0*DD);
  sem_kernel<<<dim3(NN/16,3),dim3(256),0,stream>>>(Hmp + (size_t)2*NN*DD,  Wm_[1], bm_[1], sem_sum + 2*DD);
  sem_kernel<<<dim3(NN/16,1),dim3(256),0,stream>>>(Hmp + (size_t)5*NN*DD,  Wm_[2], bm_[2], sem_sum + 5*DD);

  float* out = (float*)d_out;
  TypeInfo t0{qm_[0], sem_sum + 0*DD, 2, 0};
  TypeInfo t1{qm_[1], sem_sum + 2*DD, 3, 2};
  TypeInfo t2{qm_[2], sem_sum + 5*DD, 1, 5};
  beta_kernel<<<dim3(3),dim3(256),0,stream>>>(t0, t1, t2, out + (size_t)3*NN*DD, beta_ws);

  combine_kernel<<<dim3((NN*DD)/256,3),dim3(256),0,stream>>>(Hmp, beta_ws, out);
}

// Round 2
// 320.078 us; speedup vs baseline: 2.4125x; 2.4125x over previous
//
#include <hip/hip_runtime.h>
#include <hip/hip_bf16.h>
#include <math.h>

#define NN 2048
#define DD 256
#define KK 20
#define HH 4

struct AllMP {
  const float* xs[6][5];
  const int*   idx[6];
  const float* xt[6];
  int          P[6];
};
struct SixPtr { const float* p[6]; };
struct SemP   { const float* Wm[6]; const float* bm[6]; };

__device__ inline float wsum(float v){
  #pragma unroll
  for (int o=32;o;o>>=1) v += __shfl_xor(v,o);
  return v;
}
__device__ inline float wmax(float v){
  #pragma unroll
  for (int o=32;o;o>>=1) v = fmaxf(v,__shfl_xor(v,o));
  return v;
}

// ---------------- Kernel A: wa[m,h,d] = sum_e W[m,h,d,e]*a[m,h,e] ----------------
// grid 24 x 256: block b handles quarter (b&3) of mp (b>>2)
__global__ void wa_kernel(SixPtr W, SixPtr a, float* __restrict__ wa){
  const int m = blockIdx.x >> 2;
  const int local = ((blockIdx.x & 3) << 8) | threadIdx.x;   // 0..1023
  const int h = local >> 8, d = local & 255;
  const float4* wrow = (const float4*)(W.p[m] + (size_t)(h*DD + d)*DD);
  const float4* av   = (const float4*)(a.p[m] + h*DD);
  float acc = 0.f;
  #pragma unroll 8
  for (int e=0;e<64;e++){
    float4 wv = wrow[e], xv = av[e];
    acc += wv.x*xv.x + wv.y*xv.y + wv.z*xv.z + wv.w*xv.w;
  }
  wa[m*1024 + local] = acc;
}

// ------------- Kernel B: fused gather-max + instance attention (batched) -------------
// grid (NN, nmp); one block per (node, metapath); 256 threads (4 waves)
__launch_bounds__(256)
__global__ void inst_attn_kernel(AllMP mp, int mp_base,
                                 const float* __restrict__ wa_all,
                                 float* __restrict__ ctx){     // [nmp][N][H*D]
  __shared__ float inst_s[KK][DD];      // 20 KB
  __shared__ float wa_s[HH*DD];         // 4 KB
  __shared__ float e_s[HH][KK];
  __shared__ float alpha_s[HH][KK];
  __shared__ float s_s[HH];

  const int z = blockIdx.y;
  const int m = mp_base + z;
  const int n = blockIdx.x;
  const int t = threadIdx.x;
  const int w = t >> 6;
  const int l = t & 63;
  const int P = mp.P[m];
  const int* __restrict__ idx = mp.idx[m];

  ((float4*)wa_s)[t] = ((const float4*)(wa_all + m*1024))[t];
  __syncthreads();

  // s[h] = Xt[n]·wa[h], one head per wave
  {
    float4 xv = ((const float4*)(mp.xt[m] + (size_t)n*DD))[l];
    float4 wv = ((const float4*)(wa_s + w*DD))[l];
    float p = xv.x*wv.x + xv.y*wv.y + xv.z*wv.z + xv.w*wv.w;
    p = wsum(p);
    if (l==0) s_s[w] = p;
  }
  __syncthreads();

  for (int k = w; k < KK; k += 4) {
    const int* ib = idx + ((size_t)n*KK + k)*P;
    float4 v;
    {
      int id = ib[0];
      v = ((const float4*)(mp.xs[m][0] + (size_t)id*DD))[l];
    }
    for (int p=1;p<P;p++){
      int id = ib[p];
      float4 u = ((const float4*)(mp.xs[m][p] + (size_t)id*DD))[l];
      v.x = fmaxf(v.x,u.x); v.y = fmaxf(v.y,u.y);
      v.z = fmaxf(v.z,u.z); v.w = fmaxf(v.w,u.w);
    }
    ((float4*)(inst_s[k]))[l] = v;
    #pragma unroll
    for (int h=0;h<HH;h++){
      float4 wv = ((const float4*)(wa_s + h*DD))[l];
      float pr = v.x*wv.x + v.y*wv.y + v.z*wv.z + v.w*wv.w;
      pr = wsum(pr);
      if (l==0){
        float logit = pr + s_s[h];
        e_s[h][k] = (logit > 0.f) ? logit : 0.2f*logit;
      }
    }
  }
  __syncthreads();

  // softmax over K per head (wave w handles head w)
  {
    int h = w;
    float x = (l < KK) ? e_s[h][l] : -INFINITY;
    float mx = wmax(x);
    float pv = (l < KK) ? expf(x - mx) : 0.f;
    float sm = wsum(pv);
    if (l < KK) alpha_s[h][l] = pv / sm;
  }
  __syncthreads();

  float c0=0,c1=0,c2=0,c3=0;
  #pragma unroll
  for (int k=0;k<KK;k++){
    float iv = inst_s[k][t];
    c0 += alpha_s[0][k]*iv;
    c1 += alpha_s[1][k]*iv;
    c2 += alpha_s[2][k]*iv;
    c3 += alpha_s[3][k]*iv;
  }
  float* cb = ctx + ((size_t)z*NN + n)*(HH*DD);
  cb[0*DD + t] = c0;
  cb[1*DD + t] = c1;
  cb[2*DD + t] = c2;
  cb[3*DD + t] = c3;
}

// ---------- Kernel C: Hmp[m] = (1/H) * ctx[z][N][1024] @ W[m][1024][256] ----------
// 64x64 output tile, K staged 64 at a time in LDS. grid (32, 4, nmp), 256 thr.
__launch_bounds__(256)
__global__ void gemm_kernel(const float* __restrict__ ctx, SixPtr Wp, int mp_base,
                            float* __restrict__ Hmp){
  __shared__ float A_s[64][68];   // +4 pad: conflict-free b128 reads
  __shared__ float B_s[64][64];
  const int z = blockIdx.z;
  const int m = mp_base + z;
  const float* __restrict__ A  = ctx + (size_t)z*NN*1024;
  const float* __restrict__ Bm = Wp.p[m];
  float* __restrict__ out = Hmp + (size_t)m*NN*DD;

  const int t = threadIdx.x;
  const int n0 = blockIdx.x*64, c0 = blockIdx.y*64;
  const int r0 = (t>>4)<<2;      // 4 consecutive rows
  const int c4 = (t&15)<<2;      // 4 consecutive cols

  float4 acc0={0,0,0,0}, acc1={0,0,0,0}, acc2={0,0,0,0}, acc3={0,0,0,0};

  for (int k0=0; k0<1024; k0+=64){
    #pragma unroll
    for (int i=0;i<4;i++){
      int q = t + i*256;
      int r = q>>4;              // 0..63
      int kk = (q&15)<<2;        // 0..60
      *(float4*)&A_s[r][kk] = *(const float4*)&A[(size_t)(n0+r)*1024 + k0+kk];
      *(float4*)&B_s[r][kk] = *(const float4*)&Bm[(size_t)(k0+r)*256 + c0+kk];
    }
    __syncthreads();
    #pragma unroll 4
    for (int kk=0; kk<64; kk+=4){
      float4 a0 = *(const float4*)&A_s[r0+0][kk];
      float4 a1 = *(const float4*)&A_s[r0+1][kk];
      float4 a2 = *(const float4*)&A_s[r0+2][kk];
      float4 a3 = *(const float4*)&A_s[r0+3][kk];
      float4 b0 = *(const float4*)&B_s[kk+0][c4];
      float4 b1 = *(const float4*)&B_s[kk+1][c4];
      float4 b2 = *(const float4*)&B_s[kk+2][c4];
      float4 b3 = *(const float4*)&B_s[kk+3][c4];
      acc0.x += a0.x*b0.x + a0.y*b1.x + a0.z*b2.x + a0.w*b3.x;
      acc0.y += a0.x*b0.y + a0.y*b1.y + a0.z*b2.y + a0.w*b3.y;
      acc0.z += a0.x*b0.z + a0.y*b1.z + a0.z*b2.z + a0.w*b3.z;
      acc0.w += a0.x*b0.w + a0.y*b1.w + a0.z*b2.w + a0.w*b3.w;
      acc1.x += a1.x*b0.x + a1.y*b1.x + a1.z*b2.x + a1.w*b3.x;
      acc1.y += a1.x*b0.y + a1.y*b1.y + a1.z*b2.y + a1.w*b3.y;
      acc1.z += a1.x*b0.z + a1.y*b1.z + a1.z*b2.z + a1.w*b3.z;
      acc1.w += a1.x*b0.w + a1.y*b1.w + a1.z*b2.w + a1.w*b3.w;
      acc2.x += a2.x*b0.x + a2.y*b1.x + a2.z*b2.x + a2.w*b3.x;
      acc2.y += a2.x*b0.y + a2.y*b1.y + a2.z*b2.y + a2.w*b3.y;
      acc2.z += a2.x*b0.z + a2.y*b1.z + a2.z*b2.z + a2.w*b3.z;
      acc2.w += a2.x*b0.w + a2.y*b1.w + a2.z*b2.w + a2.w*b3.w;
      acc3.x += a3.x*b0.x + a3.y*b1.x + a3.z*b2.x + a3.w*b3.x;
      acc3.y += a3.x*b0.y + a3.y*b1.y + a3.z*b2.y + a3.w*b3.y;
      acc3.z += a3.x*b0.z + a3.y*b1.z + a3.z*b2.z + a3.w*b3.z;
      acc3.w += a3.x*b0.w + a3.y*b1.w + a3.z*b2.w + a3.w*b3.w;
    }
    __syncthreads();
  }
  const float s = 0.25f;   // 1/H
  *(float4*)&out[(size_t)(n0+r0+0)*DD + c0 + c4] = make_float4(acc0.x*s, acc0.y*s, acc0.z*s, acc0.w*s);
  *(float4*)&out[(size_t)(n0+r0+1)*DD + c0 + c4] = make_float4(acc1.x*s, acc1.y*s, acc1.z*s, acc1.w*s);
  *(float4*)&out[(size_t)(n0+r0+2)*DD + c0 + c4] = make_float4(acc2.x*s, acc2.y*s, acc2.z*s, acc2.w*s);
  *(float4*)&out[(size_t)(n0+r0+3)*DD + c0 + c4] = make_float4(acc3.x*s, acc3.y*s, acc3.z*s, acc3.w*s);
}

// ------- Kernel E: sem_sum[m,e] += sum_n tanh(H_m[n]·Wm[:,e] + bm[e]) -------
// grid (N/16, 6); 16 rows per block; thread owns column e=t
__launch_bounds__(256)
__global__ void sem_kernel(const float* __restrict__ Hmp, SemP sp,
                           float* __restrict__ sem_sum){      // [6][D]
  const int m = blockIdx.y;
  const int n0 = blockIdx.x * 16;
  const float* Hp = Hmp + (size_t)m*NN*DD + (size_t)n0*DD;
  const float* __restrict__ Wm = sp.Wm[m];
  __shared__ float h_s[16][DD];   // 16 KB
  const int t = threadIdx.x;
  const float4* src = (const float4*)Hp;
  float4* dst = (float4*)&h_s[0][0];
  #pragma unroll
  for (int i=0;i<4;i++) dst[t + i*256] = src[t + i*256];
  __syncthreads();
  float dot[16];
  #pragma unroll
  for (int r=0;r<16;r++) dot[r]=0.f;
  for (int d=0; d<DD; d++){
    float wv = Wm[(size_t)d*DD + t];
    #pragma unroll
    for (int r=0;r<16;r++) dot[r] += h_s[r][d]*wv;
  }
  float b = sp.bm[m][t];
  float acc = 0.f;
  #pragma unroll
  for (int r=0;r<16;r++) acc += tanhf(dot[r]+b);
  atomicAdd(&sem_sum[m*DD + t], acc);
}

// ---------------- Kernel F: beta softmax per node type ----------------
struct TypeInfo {
  const float* qm;
  float* sem;       // [P][D] sums
  int P;
  int beta_off;
};
__global__ void beta_kernel(TypeInfo ti0, TypeInfo ti1, TypeInfo ti2,
                            float* __restrict__ out_beta, float* __restrict__ beta_ws){
  TypeInfo ti = (blockIdx.x==0) ? ti0 : (blockIdx.x==1) ? ti1 : ti2;
  const int t = threadIdx.x;
  __shared__ float red[4];
  __shared__ float logits[3];
  float q = ti.qm[t];
  for (int p=0;p<ti.P;p++){
    float sm = ti.sem[p*DD + t] * (1.0f/NN);
    float v = tanhf(sm)*q;
    v = wsum(v);
    if ((t&63)==0) red[t>>6] = v;
    __syncthreads();
    if (t==0) logits[p] = red[0]+red[1]+red[2]+red[3];
    __syncthreads();
  }
  if (t==0){
    float mx = -INFINITY;
    for (int p=0;p<ti.P;p++) mx = fmaxf(mx, logits[p]);
    float s = 0.f, e[3];
    for (int p=0;p<ti.P;p++){ e[p] = expf(logits[p]-mx); s += e[p]; }
    for (int p=0;p<ti.P;p++){
      float b = e[p]/s;
      out_beta[ti.beta_off + p] = b;
      beta_ws[blockIdx.x*3 + p] = b;
    }
  }
}

// ---------------- Kernel G: out[n,d] = sum_p beta[p]*H_p[n,d] ----------------
__global__ void combine_kernel(const float* __restrict__ Hmp,
                               const float* __restrict__ beta_ws,
                               float* __restrict__ out){
  int type = blockIdx.y;
  int start = (type==0) ? 0 : (type==1) ? 2 : 5;
  int P = (type==0) ? 2 : (type==1) ? 3 : 1;
  size_t i = (size_t)blockIdx.x*blockDim.x + threadIdx.x;
  const float* base = Hmp + (size_t)start*NN*DD;
  float acc = 0.f;
  for (int p=0;p<P;p++) acc += beta_ws[type*3+p]*base[(size_t)p*NN*DD + i];
  out[(size_t)type*NN*DD + i] = acc;
}

extern "C" void kernel_launch(void* const* d_in, const int* in_sizes, int n_in,
                              void* d_out, int out_size, void* d_ws, size_t ws_size,
                              hipStream_t stream) {
  const float* X_drug = (const float*)d_in[0];
  const float* X_dis  = (const float*)d_in[1];
  const float* X_gene = (const float*)d_in[2];

  AllMP mp;
  for (int m=0;m<6;m++) mp.idx[m] = (const int*)d_in[3+m];
  const int P_[6] = {3,5,3,3,4,5};
  for (int m=0;m<6;m++) mp.P[m] = P_[m];
  const float* xt_[6] = {X_drug, X_drug, X_dis, X_dis, X_dis, X_gene};
  for (int m=0;m<6;m++) mp.xt[m] = xt_[m];
  const float* gp[6][5] = {
    {X_drug, X_dis, X_drug, nullptr, nullptr},
    {X_drug, X_dis, X_gene, X_dis, X_drug},
    {X_dis, X_gene, X_dis, nullptr, nullptr},
    {X_dis, X_drug, X_dis, nullptr, nullptr},
    {X_dis, X_drug, X_drug, X_dis, nullptr},
    {X_gene, X_dis, X_drug, X_dis, X_gene}};
  for (int m=0;m<6;m++) for (int p=0;p<5;p++) mp.xs[m][p] = gp[m][p];

  SixPtr Wl, al;
  for (int m=0;m<6;m++){ Wl.p[m] = (const float*)d_in[9+2*m]; al.p[m] = (const float*)d_in[10+2*m]; }
  SemP sp;
  const float* qm_[3];
  {
    const float* Wm_[3]; const float* bm_[3];
    for (int tt=0;tt<3;tt++){
      Wm_[tt] = (const float*)d_in[21+3*tt];
      bm_[tt] = (const float*)d_in[22+3*tt];
      qm_[tt] = (const float*)d_in[23+3*tt];
    }
    const int type_of[6] = {0,0,1,1,1,2};
    for (int m=0;m<6;m++){ sp.Wm[m] = Wm_[type_of[m]]; sp.bm[m] = bm_[type_of[m]]; }
  }

  // ---- workspace layout (floats) ----
  float* ws = (float*)d_ws;
  float* wa_all  = ws;                                 // 6*1024
  float* sem_sum = wa_all + 6*1024;                    // 6*256
  float* beta_ws = sem_sum + 6*DD;                     // 16
  float* Hmp     = beta_ws + 16;                       // 6*N*D = 3,145,728
  float* ctx     = Hmp + (size_t)6*NN*DD;              // B * N*1024 each

  const size_t fixed_floats = 6*1024 + 6*DD + 16 + (size_t)6*NN*DD;
  const size_t per_mp = (size_t)NN*1024;
  size_t avail = ws_size/4 > fixed_floats ? ws_size/4 - fixed_floats : 0;
  int B = (int)(avail / per_mp);
  if (B < 1) B = 1;
  if (B > 6) B = 6;

  hipMemsetAsync(sem_sum, 0, 6*DD*sizeof(float), stream);
  wa_kernel<<<dim3(24),dim3(256),0,stream>>>(Wl, al, wa_all);

  for (int g=0; g<6; g+=B){
    int nb = (6-g < B) ? (6-g) : B;
    inst_attn_kernel<<<dim3(NN,nb),dim3(256),0,stream>>>(mp, g, wa_all, ctx);
    gemm_kernel<<<dim3(32,4,nb),dim3(256),0,stream>>>(ctx, Wl, g, Hmp);
  }

  sem_kernel<<<dim3(NN/16,6),dim3(256),0,stream>>>(Hmp, sp, sem_sum);

  float* out = (float*)d_out;
  TypeInfo t0{qm_[0], sem_sum + 0*DD, 2, 0};
  TypeInfo t1{qm_[1], sem_sum + 2*DD, 3, 2};
  TypeInfo t2{qm_[2], sem_sum + 5*DD, 1, 5};
  beta_kernel<<<dim3(3),dim3(256),0,stream>>>(t0, t1, t2, out + (size_t)3*NN*DD, beta_ws);

  combine_kernel<<<dim3((NN*DD)/256,3),dim3(256),0,stream>>>(Hmp, beta_ws, out);
}

// Round 3
// 172.186 us; speedup vs baseline: 4.4847x; 1.8589x over previous
//
#include <hip/hip_runtime.h>
#include <math.h>

#define NN 2048
#define DD 256
#define KK 20
#define HH 4

typedef short short8 __attribute__((ext_vector_type(8)));
typedef float f32x4  __attribute__((ext_vector_type(4)));

struct AllMP  { const float* xs[6][5]; const int* idx[6]; const float* xt[6]; int P[6]; };
struct SixPtr { const float* p[6]; };
struct SemP   { const float* Wm[6]; const float* bm[6]; };

__device__ inline float wsum(float v){
  #pragma unroll
  for (int o=32;o;o>>=1) v += __shfl_xor(v,o);
  return v;
}
__device__ inline float wmax(float v){
  #pragma unroll
  for (int o=32;o;o>>=1) v = fmaxf(v,__shfl_xor(v,o));
  return v;
}
// reduce within 16-lane group (offsets 8,4,2,1 keep lanes inside the group)
__device__ inline float gsum16(float v){
  #pragma unroll
  for (int o=8;o;o>>=1) v += __shfl_xor(v,o);
  return v;
}
__device__ inline unsigned short f2bf(float x){
  unsigned int b = __builtin_bit_cast(unsigned int, x);
  b += 0x7FFFu + ((b>>16)&1u);          // RNE; inputs are finite
  return (unsigned short)(b>>16);
}

// ---------------- Kernel A: wa[m,h,d] = sum_e W[m,h,d,e]*a[m,h,e] ----------------
__global__ void wa_kernel(SixPtr W, SixPtr a, float* __restrict__ wa){
  const int m = blockIdx.x >> 2;
  const int local = ((blockIdx.x & 3) << 8) | threadIdx.x;
  const int h = local >> 8, d = local & 255;
  const float4* wrow = (const float4*)(W.p[m] + (size_t)(h*DD + d)*DD);
  const float4* av   = (const float4*)(a.p[m] + h*DD);
  float acc = 0.f;
  #pragma unroll 8
  for (int e=0;e<64;e++){
    float4 wv = wrow[e], xv = av[e];
    acc += wv.x*xv.x + wv.y*xv.y + wv.z*xv.z + wv.w*xv.w;
  }
  wa[m*1024 + local] = acc;
}

// ---------- Kernel W: Wt[m][e][q] = bf16(W[m][q][e])  (tile transpose) ----------
__launch_bounds__(256)
__global__ void wt_kernel(SixPtr W, unsigned short* __restrict__ Wt){
  __shared__ unsigned short T_s[64][68];
  const int m  = blockIdx.z;
  const int q0 = blockIdx.x*64, e0 = blockIdx.y*64;
  const int t  = threadIdx.x;
  const int qr = t>>4, ec = (t&15)*4;
  #pragma unroll
  for (int i=0;i<4;i++){
    float4 v = *(const float4*)(W.p[m] + (size_t)(q0+qr+i*16)*DD + e0 + ec);
    T_s[ec+0][qr+i*16]=f2bf(v.x);
    T_s[ec+1][qr+i*16]=f2bf(v.y);
    T_s[ec+2][qr+i*16]=f2bf(v.z);
    T_s[ec+3][qr+i*16]=f2bf(v.w);
  }
  __syncthreads();
  const int er = t>>4, qc = (t&15)*4;
  #pragma unroll
  for (int i=0;i<4;i++){
    unsigned short* o = Wt + ((size_t)m*256 + e0+er+i*16)*1024 + q0 + qc;
    o[0]=T_s[er+i*16][qc+0]; o[1]=T_s[er+i*16][qc+1];
    o[2]=T_s[er+i*16][qc+2]; o[3]=T_s[er+i*16][qc+3];
  }
}

// ------------- Kernel B: fused gather-max + instance attention -------------
// grid (NN, 6); 256 threads = 4 waves. Wave w owns k = 5w..5w+4 (gather+dot,
// wave-local, no barrier). wa lives in registers per 16-lane head-group.
__launch_bounds__(256)
__global__ void inst_attn_kernel(AllMP mp, const float* __restrict__ wa_all,
                                 unsigned short* __restrict__ ctxb){
  __shared__ float inst_s[KK][DD];     // 20 KB
  __shared__ int   idx_s[KK*5];
  __shared__ float e_s[KK][HH];
  __shared__ float alpha_s[KK][HH];

  const int m = blockIdx.y;
  const int n = blockIdx.x;
  const int t = threadIdx.x;
  const int w = t >> 6;
  const int l = t & 63;
  const int g = l >> 4;      // head group 0..3
  const int j = l & 15;      // lane within group
  const int P = mp.P[m];

  // idx prefetch, wave-local slice (breaks idx->gather dependent chain)
  const int* __restrict__ gidx = mp.idx[m] + (size_t)n*(KK*P);
  if (l < 5*P) idx_s[w*5*P + l] = gidx[w*5*P + l];

  // wa in registers: lane owns head g, dim-segments {j, j+16, j+32, j+48} (x4 dims)
  const float4* wab = (const float4*)(wa_all + m*1024 + g*256);
  const float4 wv0 = wab[j], wv1 = wab[j+16], wv2 = wab[j+32], wv3 = wab[j+48];

  // s_g = Xt[n]·wa[g]  (each wave computes all 4 heads; value kept in-register)
  float sg;
  {
    const float4* xb = (const float4*)(mp.xt[m] + (size_t)n*DD);
    float4 x0=xb[j], x1=xb[j+16], x2=xb[j+32], x3=xb[j+48];
    float p_ = x0.x*wv0.x + x0.y*wv0.y + x0.z*wv0.z + x0.w*wv0.w
             + x1.x*wv1.x + x1.y*wv1.y + x1.z*wv1.z + x1.w*wv1.w
             + x2.x*wv2.x + x2.y*wv2.y + x2.z*wv2.z + x2.w*wv2.w
             + x3.x*wv3.x + x3.y*wv3.y + x3.z*wv3.z + x3.w*wv3.w;
    sg = gsum16(p_);
  }

  // Phase 1: pure gather-max into LDS (lane l owns dims 4l..4l+3)
  #pragma unroll
  for (int kk=0; kk<5; kk++){
    const int k = w*5 + kk;
    const int* ib = &idx_s[k*P];
    float4 v;
    { int id = ib[0]; v = ((const float4*)(mp.xs[m][0] + (size_t)id*DD))[l]; }
    for (int p=1;p<P;p++){
      int id = ib[p];
      float4 u = ((const float4*)(mp.xs[m][p] + (size_t)id*DD))[l];
      v.x=fmaxf(v.x,u.x); v.y=fmaxf(v.y,u.y); v.z=fmaxf(v.z,u.z); v.w=fmaxf(v.w,u.w);
    }
    ((float4*)&inst_s[k][0])[l] = v;
  }

  // Phase 2: dots via 16-lane groups (4 heads in parallel, 4-stage reduce)
  #pragma unroll
  for (int kk=0; kk<5; kk++){
    const int k = w*5 + kk;
    const float4* row = (const float4*)&inst_s[k][0];
    float4 i0=row[j], i1=row[j+16], i2=row[j+32], i3=row[j+48];
    float pr = i0.x*wv0.x + i0.y*wv0.y + i0.z*wv0.z + i0.w*wv0.w
             + i1.x*wv1.x + i1.y*wv1.y + i1.z*wv1.z + i1.w*wv1.w
             + i2.x*wv2.x + i2.y*wv2.y + i2.z*wv2.z + i2.w*wv2.w
             + i3.x*wv3.x + i3.y*wv3.y + i3.z*wv3.z + i3.w*wv3.w;
    pr = gsum16(pr);
    if (j==0){
      float logit = pr + sg;
      e_s[k][g] = (logit>0.f) ? logit : 0.2f*logit;
    }
  }
  __syncthreads();

  // Phase 3: softmax over K, head w per wave
  {
    float x  = (l<KK) ? e_s[l][w] : -INFINITY;
    float mx = wmax(x);
    float pv = (l<KK) ? expf(x-mx) : 0.f;
    float sm = wsum(pv);
    if (l<KK) alpha_s[l][w] = pv/sm;
  }
  __syncthreads();

  // Phase 4: ctx[h] = sum_k alpha[h,k]*inst[k]; thread t owns column t. bf16 out.
  float c0=0,c1=0,c2=0,c3=0;
  #pragma unroll
  for (int k=0;k<KK;k++){
    float4 al = *(const float4*)&alpha_s[k][0];   // broadcast
    float iv = inst_s[k][t];
    c0 += al.x*iv; c1 += al.y*iv; c2 += al.z*iv; c3 += al.w*iv;
  }
  unsigned short* cb = ctxb + ((size_t)m*NN + n)*1024;
  cb[0*DD+t]=f2bf(c0); cb[1*DD+t]=f2bf(c1); cb[2*DD+t]=f2bf(c2); cb[3*DD+t]=f2bf(c3);
}

// ---------- Kernel C: Hmp[m] = (1/H) * ctx_bf16[N][1024] @ W_bf16  (MFMA) ----------
// 64x64 tile, BK=64, 4 waves (2x2), each wave 32x32 = 2x2 frags of 16x16x32.
// XOR-swizzled LDS (T2): element (row,k) at col (k/8 ^ (row&7))*8 + k%8.
__launch_bounds__(256)
__global__ void gemm_kernel(const unsigned short* __restrict__ ctxb,
                            const unsigned short* __restrict__ Wt,
                            float* __restrict__ Hmp){
  __shared__ unsigned short A_s[64][64];   // 8 KB
  __shared__ unsigned short B_s[64][64];   // 8 KB (holds Bt rows = output cols)
  const int m  = blockIdx.z;
  const int n0 = blockIdx.x*64, c0 = blockIdx.y*64;
  const int t  = threadIdx.x;
  const int l  = t & 63;
  const int wid  = t >> 6;
  const int wrow = wid & 1, wcol = wid >> 1;
  const unsigned short* Abase = ctxb + (size_t)m*NN*1024;
  const unsigned short* Bbase = Wt   + (size_t)m*256*1024;

  f32x4 acc[2][2] = {};
  const int srow = t>>3, sseg = t&7;

  for (int k0=0; k0<1024; k0+=64){
    #pragma unroll
    for (int r=0;r<2;r++){
      const int row = srow + r*32;
      int4 av = *(const int4*)(Abase + (size_t)(n0+row)*1024 + k0 + sseg*8);
      *(int4*)&A_s[row][(sseg ^ (row&7))*8] = av;
      int4 bv = *(const int4*)(Bbase + (size_t)(c0+row)*1024 + k0 + sseg*8);
      *(int4*)&B_s[row][(sseg ^ (row&7))*8] = bv;
    }
    __syncthreads();
    #pragma unroll
    for (int kf=0;kf<2;kf++){
      short8 a[2], b[2];
      const int s = kf*4 + (l>>4);
      #pragma unroll
      for (int mr=0;mr<2;mr++){
        const int row = wrow*32 + mr*16 + (l&15);
        a[mr] = *(const short8*)&A_s[row][(s ^ (row&7))*8];
      }
      #pragma unroll
      for (int nr=0;nr<2;nr++){
        const int col = wcol*32 + nr*16 + (l&15);
        b[nr] = *(const short8*)&B_s[col][(s ^ (col&7))*8];
      }
      #pragma unroll
      for (int mr=0;mr<2;mr++)
        #pragma unroll
        for (int nr=0;nr<2;nr++)
          acc[mr][nr] = __builtin_amdgcn_mfma_f32_16x16x32_bf16(a[mr], b[nr], acc[mr][nr], 0,0,0);
    }
    __syncthreads();
  }
  float* out = Hmp + (size_t)m*NN*DD;
  #pragma unroll
  for (int mr=0;mr<2;mr++){
    const int rbase = n0 + wrow*32 + mr*16 + (l>>4)*4;
    #pragma unroll
    for (int nr=0;nr<2;nr++){
      const int col = c0 + wcol*32 + nr*16 + (l&15);
      #pragma unroll
      for (int r=0;r<4;r++)
        out[(size_t)(rbase+r)*DD + col] = acc[mr][nr][r]*0.25f;   // 1/H
    }
  }
}

// ------- Kernel E: sem_sum[m,e] += sum_n tanh(H_m[n]·Wm[:,e] + bm[e]) -------
__launch_bounds__(256)
__global__ void sem_kernel(const float* __restrict__ Hmp, SemP sp,
                           float* __restrict__ sem_sum){
  const int m = blockIdx.y;
  const int n0 = blockIdx.x * 16;
  const float* Hp = Hmp + (size_t)m*NN*DD + (size_t)n0*DD;
  const float* __restrict__ Wm = sp.Wm[m];
  __shared__ float h_s[16][DD];
  const int t = threadIdx.x;
  const float4* src = (const float4*)Hp;
  float4* dst = (float4*)&h_s[0][0];
  #pragma unroll
  for (int i=0;i<4;i++) dst[t + i*256] = src[t + i*256];
  __syncthreads();
  float dot[16];
  #pragma unroll
  for (int r=0;r<16;r++) dot[r]=0.f;
  for (int d=0; d<DD; d++){
    float wv = Wm[(size_t)d*DD + t];
    #pragma unroll
    for (int r=0;r<16;r++) dot[r] += h_s[r][d]*wv;
  }
  float b = sp.bm[m][t];
  float acc = 0.f;
  #pragma unroll
  for (int r=0;r<16;r++) acc += tanhf(dot[r]+b);
  atomicAdd(&sem_sum[m*DD + t], acc);
}

// ---------------- Kernel F: beta softmax per node type ----------------
struct TypeInfo { const float* qm; float* sem; int P; int beta_off; };
__global__ void beta_kernel(TypeInfo ti0, TypeInfo ti1, TypeInfo ti2,
                            float* __restrict__ out_beta, float* __restrict__ beta_ws){
  TypeInfo ti = (blockIdx.x==0) ? ti0 : (blockIdx.x==1) ? ti1 : ti2;
  const int t = threadIdx.x;
  __shared__ float red[4];
  __shared__ float logits[3];
  float q = ti.qm[t];
  for (int p=0;p<ti.P;p++){
    float sm = ti.sem[p*DD + t] * (1.0f/NN);
    float v = tanhf(sm)*q;
    v = wsum(v);
    if ((t&63)==0) red[t>>6] = v;
    __syncthreads();
    if (t==0) logits[p] = red[0]+red[1]+red[2]+red[3];
    __syncthreads();
  }
  if (t==0){
    float mx = -INFINITY;
    for (int p=0;p<ti.P;p++) mx = fmaxf(mx, logits[p]);
    float s = 0.f, e[3];
    for (int p=0;p<ti.P;p++){ e[p] = expf(logits[p]-mx); s += e[p]; }
    for (int p=0;p<ti.P;p++){
      float b = e[p]/s;
      out_beta[ti.beta_off + p] = b;
      beta_ws[blockIdx.x*3 + p] = b;
    }
  }
}

// ---------------- Kernel G: out[n,d] = sum_p beta[p]*H_p[n,d] ----------------
__global__ void combine_kernel(const float* __restrict__ Hmp,
                               const float* __restrict__ beta_ws,
                               float* __restrict__ out){
  int type = blockIdx.y;
  int start = (type==0) ? 0 : (type==1) ? 2 : 5;
  int P = (type==0) ? 2 : (type==1) ? 3 : 1;
  size_t i = (size_t)blockIdx.x*blockDim.x + threadIdx.x;
  const float* base = Hmp + (size_t)start*NN*DD;
  float acc = 0.f;
  for (int p=0;p<P;p++) acc += beta_ws[type*3+p]*base[(size_t)p*NN*DD + i];
  out[(size_t)type*NN*DD + i] = acc;
}

extern "C" void kernel_launch(void* const* d_in, const int* in_sizes, int n_in,
                              void* d_out, int out_size, void* d_ws, size_t ws_size,
                              hipStream_t stream) {
  const float* X_drug = (const float*)d_in[0];
  const float* X_dis  = (const float*)d_in[1];
  const float* X_gene = (const float*)d_in[2];

  AllMP mp;
  for (int m=0;m<6;m++) mp.idx[m] = (const int*)d_in[3+m];
  const int P_[6] = {3,5,3,3,4,5};
  for (int m=0;m<6;m++) mp.P[m] = P_[m];
  const float* xt_[6] = {X_drug, X_drug, X_dis, X_dis, X_dis, X_gene};
  for (int m=0;m<6;m++) mp.xt[m] = xt_[m];
  const float* gp[6][5] = {
    {X_drug, X_dis, X_drug, nullptr, nullptr},
    {X_drug, X_dis, X_gene, X_dis, X_drug},
    {X_dis, X_gene, X_dis, nullptr, nullptr},
    {X_dis, X_drug, X_dis, nullptr, nullptr},
    {X_dis, X_drug, X_drug, X_dis, nullptr},
    {X_gene, X_dis, X_drug, X_dis, X_gene}};
  for (int m=0;m<6;m++) for (int p=0;p<5;p++) mp.xs[m][p] = gp[m][p];

  SixPtr Wl, al;
  for (int m=0;m<6;m++){ Wl.p[m] = (const float*)d_in[9+2*m]; al.p[m] = (const float*)d_in[10+2*m]; }
  SemP sp;
  const float* qm_[3];
  {
    const float* Wm_[3]; const float* bm_[3];
    for (int tt=0;tt<3;tt++){
      Wm_[tt] = (const float*)d_in[21+3*tt];
      bm_[tt] = (const float*)d_in[22+3*tt];
      qm_[tt] = (const float*)d_in[23+3*tt];
    }
    const int type_of[6] = {0,0,1,1,1,2};
    for (int m=0;m<6;m++){ sp.Wm[m] = Wm_[type_of[m]]; sp.bm[m] = bm_[type_of[m]]; }
  }

  // ---- workspace layout: ~41 MB (ws proven >= 63 MB by round-1 B=6 path) ----
  float* ws = (float*)d_ws;
  float* wa_all  = ws;                                   // 6*1024
  float* sem_sum = wa_all + 6*1024;                      // 6*256
  float* beta_ws = sem_sum + 6*DD;                       // 16
  float* Hmp     = beta_ws + 16;                         // 6*N*D fp32
  unsigned short* Wt   = (unsigned short*)(Hmp + (size_t)6*NN*DD);   // 6*256*1024 bf16
  unsigned short* ctxb = Wt + (size_t)6*256*1024;                    // 6*N*1024 bf16

  hipMemsetAsync(sem_sum, 0, 6*DD*sizeof(float), stream);
  wa_kernel<<<dim3(24),dim3(256),0,stream>>>(Wl, al, wa_all);
  wt_kernel<<<dim3(16,4,6),dim3(256),0,stream>>>(Wl, Wt);

  inst_attn_kernel<<<dim3(NN,6),dim3(256),0,stream>>>(mp, wa_all, ctxb);
  gemm_kernel<<<dim3(32,4,6),dim3(256),0,stream>>>(ctxb, Wt, Hmp);

  sem_kernel<<<dim3(NN/16,6),dim3(256),0,stream>>>(Hmp, sp, sem_sum);

  float* out = (float*)d_out;
  TypeInfo t0{qm_[0], sem_sum + 0*DD, 2, 0};
  TypeInfo t1{qm_[1], sem_sum + 2*DD, 3, 2};
  TypeInfo t2{qm_[2], sem_sum + 5*DD, 1, 5};
  beta_kernel<<<dim3(3),dim3(256),0,stream>>>(t0, t1, t2, out + (size_t)3*NN*DD, beta_ws);

  combine_kernel<<<dim3((NN*DD)/256,3),dim3(256),0,stream>>>(Hmp, beta_ws, out);
}

// Round 4
// 158.306 us; speedup vs baseline: 4.8779x; 1.0877x over previous
//
#include <hip/hip_runtime.h>
#include <math.h>

#define NN 2048
#define DD 256
#define KK 20
#define HH 4

typedef short short8 __attribute__((ext_vector_type(8)));
typedef float f32x4  __attribute__((ext_vector_type(4)));

struct AllMP  { const unsigned short* xs[6][5]; const int* idx[6]; const unsigned short* xt[6]; int P[6]; };
struct SixPtr { const float* p[6]; };
struct SemB   { const unsigned short* Wmt[6]; const float* bm[6]; };

__device__ inline float wsum(float v){
  #pragma unroll
  for (int o=32;o;o>>=1) v += __shfl_xor(v,o);
  return v;
}
__device__ inline float wmax(float v){
  #pragma unroll
  for (int o=32;o;o>>=1) v = fmaxf(v,__shfl_xor(v,o));
  return v;
}
__device__ inline float gsum16(float v){
  #pragma unroll
  for (int o=8;o;o>>=1) v += __shfl_xor(v,o);
  return v;
}
__device__ inline unsigned short f2bf(float x){
  unsigned int b = __builtin_bit_cast(unsigned int, x);
  b += 0x7FFFu + ((b>>16)&1u);
  return (unsigned short)(b>>16);
}
__device__ inline float bf2f(unsigned short u){
  return __builtin_bit_cast(float, (unsigned int)u << 16);
}
__device__ inline float4 ld_bf4(const unsigned short* p){
  ushort4 u = *(const ushort4*)p;
  return make_float4(bf2f(u.x), bf2f(u.y), bf2f(u.z), bf2f(u.w));
}

// ---------------- Kernel A: wa[m,h,d] = sum_e W[m,h,d,e]*a[m,h,e] ----------------
__global__ void wa_kernel(SixPtr W, SixPtr a, float* __restrict__ wa){
  const int m = blockIdx.x >> 2;
  const int local = ((blockIdx.x & 3) << 8) | threadIdx.x;
  const int h = local >> 8, d = local & 255;
  const float4* wrow = (const float4*)(W.p[m] + (size_t)(h*DD + d)*DD);
  const float4* av   = (const float4*)(a.p[m] + h*DD);
  float acc = 0.f;
  #pragma unroll 8
  for (int e=0;e<64;e++){
    float4 wv = wrow[e], xv = av[e];
    acc += wv.x*xv.x + wv.y*xv.y + wv.z*xv.z + wv.w*xv.w;
  }
  wa[m*1024 + local] = acc;
}

// ---------- Kernel X: bf16 copies of the three feature tables ----------
__global__ void xconv_kernel(SixPtr X, unsigned short* __restrict__ Xb){
  int gid = blockIdx.x*256 + threadIdx.x;   // 0 .. 3*131072-1
  int tb  = gid >> 17;
  int off = gid & 131071;
  float4 v = ((const float4*)X.p[tb])[off];
  ushort4 o = { f2bf(v.x), f2bf(v.y), f2bf(v.z), f2bf(v.w) };
  ((ushort4*)(Xb + (size_t)tb*NN*DD))[off] = o;
}

// ---------- Kernel T: out[m][c][r] = bf16(in[m][r][c])  (transpose+convert) ----------
__launch_bounds__(256)
__global__ void transconv_kernel(SixPtr in, int R, int C, unsigned short* __restrict__ out){
  __shared__ unsigned short T_s[64][68];
  const int m  = blockIdx.z;
  const int r0 = blockIdx.x*64, c0 = blockIdx.y*64;
  const int t  = threadIdx.x;
  const int rr = t>>4, cc = (t&15)*4;
  const float* src = in.p[m];
  #pragma unroll
  for (int i=0;i<4;i++){
    float4 v = *(const float4*)(src + (size_t)(r0+rr+i*16)*C + c0 + cc);
    T_s[cc+0][rr+i*16]=f2bf(v.x);
    T_s[cc+1][rr+i*16]=f2bf(v.y);
    T_s[cc+2][rr+i*16]=f2bf(v.z);
    T_s[cc+3][rr+i*16]=f2bf(v.w);
  }
  __syncthreads();
  const int cr = t>>4, rc = (t&15)*4;
  unsigned short* ob = out + (size_t)m*R*C;
  #pragma unroll
  for (int i=0;i<4;i++){
    ushort4 v = { T_s[cr+i*16][rc+0], T_s[cr+i*16][rc+1],
                  T_s[cr+i*16][rc+2], T_s[cr+i*16][rc+3] };
    *(ushort4*)(ob + (size_t)(c0+cr+i*16)*R + r0 + rc) = v;
  }
}

// ------------- Kernel B: fused gather-max + instance attention -------------
template<int P>
__device__ inline void gather_dot(const AllMP& mp, int m, int w, int l, int g, int j,
                                  const int* idx_s, float (*inst_s)[DD],
                                  float4 wv0, float4 wv1, float4 wv2, float4 wv3,
                                  float sg, float (*e_s)[HH]){
  #pragma unroll
  for (int kk=0; kk<5; kk++){
    const int k = w*5 + kk;
    const int* ib = &idx_s[k*P];
    float4 v = ld_bf4(mp.xs[m][0] + (size_t)ib[0]*DD + 4*l);
    #pragma unroll
    for (int p=1;p<P;p++){
      float4 u = ld_bf4(mp.xs[m][p] + (size_t)ib[p]*DD + 4*l);
      v.x=fmaxf(v.x,u.x); v.y=fmaxf(v.y,u.y); v.z=fmaxf(v.z,u.z); v.w=fmaxf(v.w,u.w);
    }
    ((float4*)&inst_s[k][0])[l] = v;
  }
  #pragma unroll
  for (int kk=0; kk<5; kk++){
    const int k = w*5 + kk;
    const float4* row = (const float4*)&inst_s[k][0];
    float4 i0=row[j], i1=row[j+16], i2=row[j+32], i3=row[j+48];
    float pr = i0.x*wv0.x + i0.y*wv0.y + i0.z*wv0.z + i0.w*wv0.w
             + i1.x*wv1.x + i1.y*wv1.y + i1.z*wv1.z + i1.w*wv1.w
             + i2.x*wv2.x + i2.y*wv2.y + i2.z*wv2.z + i2.w*wv2.w
             + i3.x*wv3.x + i3.y*wv3.y + i3.z*wv3.z + i3.w*wv3.w;
    pr = gsum16(pr);
    if (j==0){
      float logit = pr + sg;
      e_s[k][g] = (logit>0.f) ? logit : 0.2f*logit;
    }
  }
}

__launch_bounds__(256)
__global__ void inst_attn_kernel(AllMP mp, int mp_base, const float* __restrict__ wa_all,
                                 unsigned short* __restrict__ ctxb){
  __shared__ float inst_s[KK][DD];     // 20 KB
  __shared__ int   idx_s[KK*5];
  __shared__ float e_s[KK][HH];
  __shared__ float alpha_s[KK][HH];

  const int z = blockIdx.y;
  const int m = mp_base + z;
  const int n = blockIdx.x;
  const int t = threadIdx.x;
  const int w = t >> 6;
  const int l = t & 63;
  const int g = l >> 4;
  const int j = l & 15;
  const int P = mp.P[m];

  const int* __restrict__ gidx = mp.idx[m] + (size_t)n*(KK*P);
  if (l < 5*P) idx_s[w*5*P + l] = gidx[w*5*P + l];

  const float4* wab = (const float4*)(wa_all + m*1024 + g*256);
  const float4 wv0 = wab[j], wv1 = wab[j+16], wv2 = wab[j+32], wv3 = wab[j+48];

  float sg;
  {
    const unsigned short* xb = mp.xt[m] + (size_t)n*DD;
    float4 x0=ld_bf4(xb+4*j), x1=ld_bf4(xb+4*(j+16)), x2=ld_bf4(xb+4*(j+32)), x3=ld_bf4(xb+4*(j+48));
    float p_ = x0.x*wv0.x + x0.y*wv0.y + x0.z*wv0.z + x0.w*wv0.w
             + x1.x*wv1.x + x1.y*wv1.y + x1.z*wv1.z + x1.w*wv1.w
             + x2.x*wv2.x + x2.y*wv2.y + x2.z*wv2.z + x2.w*wv2.w
             + x3.x*wv3.x + x3.y*wv3.y + x3.z*wv3.z + x3.w*wv3.w;
    sg = gsum16(p_);
  }

  switch(P){
    case 3: gather_dot<3>(mp,m,w,l,g,j,idx_s,inst_s,wv0,wv1,wv2,wv3,sg,e_s); break;
    case 4: gather_dot<4>(mp,m,w,l,g,j,idx_s,inst_s,wv0,wv1,wv2,wv3,sg,e_s); break;
    default: gather_dot<5>(mp,m,w,l,g,j,idx_s,inst_s,wv0,wv1,wv2,wv3,sg,e_s); break;
  }
  __syncthreads();

  {
    float x  = (l<KK) ? e_s[l][w] : -INFINITY;
    float mx = wmax(x);
    float pv = (l<KK) ? expf(x-mx) : 0.f;
    float sm = wsum(pv);
    if (l<KK) alpha_s[l][w] = pv/sm;
  }
  __syncthreads();

  float c0=0,c1=0,c2=0,c3=0;
  #pragma unroll
  for (int k=0;k<KK;k++){
    float4 al = *(const float4*)&alpha_s[k][0];
    float iv = inst_s[k][t];
    c0 += al.x*iv; c1 += al.y*iv; c2 += al.z*iv; c3 += al.w*iv;
  }
  unsigned short* cb = ctxb + ((size_t)z*NN + n)*1024;
  cb[0*DD+t]=f2bf(c0); cb[1*DD+t]=f2bf(c1); cb[2*DD+t]=f2bf(c2); cb[3*DD+t]=f2bf(c3);
}

// ---------- Kernel C: Hmp[m] = (1/H) * ctx_bf16 @ W_bf16  (MFMA) ----------
__launch_bounds__(256)
__global__ void gemm_kernel(const unsigned short* __restrict__ ctxb,
                            const unsigned short* __restrict__ Wt, int mp_base,
                            float* __restrict__ Hmp){
  __shared__ unsigned short A_s[64][64];
  __shared__ unsigned short B_s[64][64];
  const int z  = blockIdx.z;
  const int m  = mp_base + z;
  const int n0 = blockIdx.x*64, c0 = blockIdx.y*64;
  const int t  = threadIdx.x;
  const int l  = t & 63;
  const int wid  = t >> 6;
  const int wrow = wid & 1, wcol = wid >> 1;
  const unsigned short* Abase = ctxb + (size_t)z*NN*1024;
  const unsigned short* Bbase = Wt   + (size_t)m*256*1024;

  f32x4 acc[2][2] = {};
  const int srow = t>>3, sseg = t&7;

  for (int k0=0; k0<1024; k0+=64){
    #pragma unroll
    for (int r=0;r<2;r++){
      const int row = srow + r*32;
      int4 av = *(const int4*)(Abase + (size_t)(n0+row)*1024 + k0 + sseg*8);
      *(int4*)&A_s[row][(sseg ^ (row&7))*8] = av;
      int4 bv = *(const int4*)(Bbase + (size_t)(c0+row)*1024 + k0 + sseg*8);
      *(int4*)&B_s[row][(sseg ^ (row&7))*8] = bv;
    }
    __syncthreads();
    #pragma unroll
    for (int kf=0;kf<2;kf++){
      short8 a[2], b[2];
      const int s = kf*4 + (l>>4);
      #pragma unroll
      for (int mr=0;mr<2;mr++){
        const int row = wrow*32 + mr*16 + (l&15);
        a[mr] = *(const short8*)&A_s[row][(s ^ (row&7))*8];
      }
      #pragma unroll
      for (int nr=0;nr<2;nr++){
        const int col = wcol*32 + nr*16 + (l&15);
        b[nr] = *(const short8*)&B_s[col][(s ^ (col&7))*8];
      }
      #pragma unroll
      for (int mr=0;mr<2;mr++)
        #pragma unroll
        for (int nr=0;nr<2;nr++)
          acc[mr][nr] = __builtin_amdgcn_mfma_f32_16x16x32_bf16(a[mr], b[nr], acc[mr][nr], 0,0,0);
    }
    __syncthreads();
  }
  float* out = Hmp + (size_t)m*NN*DD;
  #pragma unroll
  for (int mr=0;mr<2;mr++){
    const int rbase = n0 + wrow*32 + mr*16 + (l>>4)*4;
    #pragma unroll
    for (int nr=0;nr<2;nr++){
      const int col = c0 + wcol*32 + nr*16 + (l&15);
      #pragma unroll
      for (int r=0;r<4;r++)
        out[(size_t)(rbase+r)*DD + col] = acc[mr][nr][r]*0.25f;
    }
  }
}

// ------- Kernel E (MFMA): sem_sum[m,e] += sum_n tanh(Hmp[m,n,:]·Wm[:,e] + bm[e]) -------
__launch_bounds__(256)
__global__ void sem_kernel(const float* __restrict__ Hmp, SemB sb,
                           float* __restrict__ sem_sum){
  __shared__ unsigned short A_s[64][256];   // 32 KB, swizzled
  __shared__ unsigned short B_s[64][256];   // 32 KB, swizzled
  const int m  = blockIdx.z;
  const int n0 = blockIdx.x*64, c0 = blockIdx.y*64;
  const int t  = threadIdx.x, l = t & 63, wid = t >> 6;
  const int wrow = wid & 1, wcol = wid >> 1;
  const float* Ab = Hmp + (size_t)m*NN*DD;
  const unsigned short* Bb = sb.Wmt[m];

  #pragma unroll
  for (int i=0;i<16;i++){
    int q = t + i*256;
    int row = q>>6, c4 = (q&63)<<2;
    float4 v = *(const float4*)(Ab + (size_t)(n0+row)*DD + c4);
    ushort4 o = { f2bf(v.x), f2bf(v.y), f2bf(v.z), f2bf(v.w) };
    int seg8 = c4>>3, half = (c4>>2)&1;
    int segs = (seg8 & 24) | ((seg8&7) ^ (row&7));
    *(ushort4*)((char*)&A_s[0][0] + row*512 + segs*16 + half*8) = o;
  }
  #pragma unroll
  for (int i=0;i<8;i++){
    int q = t + i*256;
    int row = q>>5, seg = q&31;
    int4 v = *(const int4*)(Bb + (size_t)(c0+row)*DD + seg*8);
    int segs = (seg&24) | ((seg&7)^(row&7));
    *(int4*)((char*)&B_s[0][0] + row*512 + segs*16) = v;
  }
  __syncthreads();

  f32x4 acc[2][2] = {};
  #pragma unroll
  for (int kf=0; kf<8; kf++){
    const int s = kf*4 + (l>>4);
    short8 a[2], b[2];
    #pragma unroll
    for (int mr=0;mr<2;mr++){
      int row = wrow*32 + mr*16 + (l&15);
      int ss = (s&24) | ((s&7)^(row&7));
      a[mr] = *(const short8*)((const char*)&A_s[0][0] + row*512 + ss*16);
    }
    #pragma unroll
    for (int nr=0;nr<2;nr++){
      int row = wcol*32 + nr*16 + (l&15);
      int ss = (s&24) | ((s&7)^(row&7));
      b[nr] = *(const short8*)((const char*)&B_s[0][0] + row*512 + ss*16);
    }
    #pragma unroll
    for (int mr=0;mr<2;mr++)
      #pragma unroll
      for (int nr=0;nr<2;nr++)
        acc[mr][nr] = __builtin_amdgcn_mfma_f32_16x16x32_bf16(a[mr], b[nr], acc[mr][nr], 0,0,0);
  }

  #pragma unroll
  for (int nr=0;nr<2;nr++){
    const int col = c0 + wcol*32 + nr*16 + (l&15);
    float b = sb.bm[m][col];
    float sv = 0.f;
    #pragma unroll
    for (int mr=0;mr<2;mr++)
      #pragma unroll
      for (int r=0;r<4;r++)
        sv += tanhf(acc[mr][nr][r] + b);
    sv += __shfl_xor(sv,16);
    sv += __shfl_xor(sv,32);
    if (l < 16) atomicAdd(&sem_sum[m*DD + col], sv);
  }
}

// ---------------- Kernel F: beta softmax per node type ----------------
struct TypeInfo { const float* qm; float* sem; int P; int beta_off; };
__global__ void beta_kernel(TypeInfo ti0, TypeInfo ti1, TypeInfo ti2,
                            float* __restrict__ out_beta, float* __restrict__ beta_ws){
  TypeInfo ti = (blockIdx.x==0) ? ti0 : (blockIdx.x==1) ? ti1 : ti2;
  const int t = threadIdx.x;
  __shared__ float red[4];
  __shared__ float logits[3];
  float q = ti.qm[t];
  for (int p=0;p<ti.P;p++){
    float sm = ti.sem[p*DD + t] * (1.0f/NN);
    float v = tanhf(sm)*q;
    v = wsum(v);
    if ((t&63)==0) red[t>>6] = v;
    __syncthreads();
    if (t==0) logits[p] = red[0]+red[1]+red[2]+red[3];
    __syncthreads();
  }
  if (t==0){
    float mx = -INFINITY;
    for (int p=0;p<ti.P;p++) mx = fmaxf(mx, logits[p]);
    float s = 0.f, e[3];
    for (int p=0;p<ti.P;p++){ e[p] = expf(logits[p]-mx); s += e[p]; }
    for (int p=0;p<ti.P;p++){
      float b = e[p]/s;
      out_beta[ti.beta_off + p] = b;
      beta_ws[blockIdx.x*3 + p] = b;
    }
  }
}

// ---------------- Kernel G: out[n,d] = sum_p beta[p]*H_p[n,d] ----------------
__global__ void combine_kernel(const float* __restrict__ Hmp,
                               const float* __restrict__ beta_ws,
                               float* __restrict__ out){
  int type = blockIdx.y;
  int start = (type==0) ? 0 : (type==1) ? 2 : 5;
  int P = (type==0) ? 2 : (type==1) ? 3 : 1;
  size_t i = (size_t)blockIdx.x*blockDim.x + threadIdx.x;
  const float* base = Hmp + (size_t)start*NN*DD;
  float acc = 0.f;
  for (int p=0;p<P;p++) acc += beta_ws[type*3+p]*base[(size_t)p*NN*DD + i];
  out[(size_t)type*NN*DD + i] = acc;
}

extern "C" void kernel_launch(void* const* d_in, const int* in_sizes, int n_in,
                              void* d_out, int out_size, void* d_ws, size_t ws_size,
                              hipStream_t stream) {
  SixPtr Xp; Xp.p[0]=(const float*)d_in[0]; Xp.p[1]=(const float*)d_in[1]; Xp.p[2]=(const float*)d_in[2];
  for (int i=3;i<6;i++) Xp.p[i]=Xp.p[0];

  SixPtr Wl, al;
  for (int m=0;m<6;m++){ Wl.p[m] = (const float*)d_in[9+2*m]; al.p[m] = (const float*)d_in[10+2*m]; }
  const float* Wm_[3]; const float* bm_[3]; const float* qm_[3];
  for (int tt=0;tt<3;tt++){
    Wm_[tt] = (const float*)d_in[21+3*tt];
    bm_[tt] = (const float*)d_in[22+3*tt];
    qm_[tt] = (const float*)d_in[23+3*tt];
  }
  SixPtr Wm3; for (int i=0;i<6;i++) Wm3.p[i] = Wm_[i<3?i:0];

  // ---- workspace layout (ws proven >= 41 MB; this uses ~32 MB) ----
  char* ws = (char*)d_ws;
  float* wa_all  = (float*)ws;                               ws += 6*1024*4;
  float* sem_sum = (float*)ws;                               ws += 6*DD*4;
  float* beta_ws = (float*)ws;                               ws += 16*4;
  float* Hmp     = (float*)ws;                               ws += (size_t)6*NN*DD*4;
  unsigned short* Wt   = (unsigned short*)ws;                ws += (size_t)6*256*1024*2;
  unsigned short* Wmt  = (unsigned short*)ws;                ws += (size_t)3*256*256*2;
  unsigned short* Xb   = (unsigned short*)ws;                ws += (size_t)3*NN*DD*2;
  unsigned short* ctxb = (unsigned short*)ws;                // 3*NN*1024*2

  AllMP mp;
  for (int m=0;m<6;m++) mp.idx[m] = (const int*)d_in[3+m];
  const int P_[6] = {3,5,3,3,4,5};
  for (int m=0;m<6;m++) mp.P[m] = P_[m];
  const int xt_t[6] = {0,0,1,1,1,2};
  const int gp_t[6][5] = {
    {0,1,0,0,0}, {0,1,2,1,0}, {1,2,1,1,1},
    {1,0,1,1,1}, {1,0,0,1,1}, {2,1,0,1,2}};
  for (int m=0;m<6;m++){
    mp.xt[m] = Xb + (size_t)xt_t[m]*NN*DD;
    for (int p=0;p<5;p++) mp.xs[m][p] = Xb + (size_t)gp_t[m][p]*NN*DD;
  }

  SemB sb;
  const int type_of[6] = {0,0,1,1,1,2};
  for (int m=0;m<6;m++){
    sb.Wmt[m] = Wmt + (size_t)type_of[m]*256*256;
    sb.bm[m]  = bm_[type_of[m]];
  }

  hipMemsetAsync(sem_sum, 0, 6*DD*sizeof(float), stream);
  wa_kernel<<<dim3(24),dim3(256),0,stream>>>(Wl, al, wa_all);
  xconv_kernel<<<dim3(1536),dim3(256),0,stream>>>(Xp, Xb);
  transconv_kernel<<<dim3(16,4,6),dim3(256),0,stream>>>(Wl, 1024, 256, Wt);
  transconv_kernel<<<dim3(4,4,3),dim3(256),0,stream>>>(Wm3, 256, 256, Wmt);

  for (int g=0; g<6; g+=3){
    inst_attn_kernel<<<dim3(NN,3),dim3(256),0,stream>>>(mp, g, wa_all, ctxb);
    gemm_kernel<<<dim3(32,4,3),dim3(256),0,stream>>>(ctxb, Wt, g, Hmp);
  }

  sem_kernel<<<dim3(32,4,6),dim3(256),0,stream>>>(Hmp, sb, sem_sum);

  float* out = (float*)d_out;
  TypeInfo t0{qm_[0], sem_sum + 0*DD, 2, 0};
  TypeInfo t1{qm_[1], sem_sum + 2*DD, 3, 2};
  TypeInfo t2{qm_[2], sem_sum + 5*DD, 1, 5};
  beta_kernel<<<dim3(3),dim3(256),0,stream>>>(t0, t1, t2, out + (size_t)3*NN*DD, beta_ws);

  combine_kernel<<<dim3((NN*DD)/256,3),dim3(256),0,stream>>>(Hmp, beta_ws, out);
}

// Round 5
// 132.010 us; speedup vs baseline: 5.8496x; 1.1992x over previous
//
#include <hip/hip_runtime.h>
#include <math.h>

#define NN 2048
#define DD 256
#define KK 20
#define HH 4

typedef short short8 __attribute__((ext_vector_type(8)));
typedef float f32x4  __attribute__((ext_vector_type(4)));
typedef _Float16 half8 __attribute__((ext_vector_type(8)));
typedef _Float16 h2    __attribute__((ext_vector_type(2)));

#if defined(__has_builtin)
#  if __has_builtin(__builtin_amdgcn_fdot2)
#    define HAS_FDOT2 1
#  else
#    define HAS_FDOT2 0
#  endif
#else
#  define HAS_FDOT2 0
#endif

struct AllMP  { const unsigned short* xs[6][5]; const int* idx[6]; const unsigned short* xt[6]; int P[6]; };
struct SixPtr { const float* p[6]; };
struct SemB   { const unsigned short* Wmt[6]; const float* bm[6]; };

__device__ inline float wsum(float v){
  #pragma unroll
  for (int o=32;o;o>>=1) v += __shfl_xor(v,o);
  return v;
}
__device__ inline float wmax(float v){
  #pragma unroll
  for (int o=32;o;o>>=1) v = fmaxf(v,__shfl_xor(v,o));
  return v;
}
__device__ inline float gsum16(float v){
  #pragma unroll
  for (int o=8;o;o>>=1) v += __shfl_xor(v,o);
  return v;
}
__device__ inline unsigned short f2h(float x){
  return __builtin_bit_cast(unsigned short, (_Float16)x);
}
__device__ inline h2 bch2(unsigned int u){ return __builtin_bit_cast(h2, u); }
__device__ inline unsigned int bcu(h2 v){ return __builtin_bit_cast(unsigned int, v); }
__device__ inline h2 packh2(float a, float b){ h2 r; r[0]=(_Float16)a; r[1]=(_Float16)b; return r; }
__device__ inline h2 hmax2(h2 a, h2 b){
  unsigned int d, ua = bcu(a), ub = bcu(b);
  asm("v_pk_max_f16 %0, %1, %2" : "=v"(d) : "v"(ua), "v"(ub));
  return bch2(d);
}
__device__ inline float dot2(h2 a, h2 b, float c){
#if HAS_FDOT2
  return __builtin_amdgcn_fdot2(a, b, c, false);
#else
  return c + (float)a[0]*(float)b[0] + (float)a[1]*(float)b[1];
#endif
}

// ------- Kernel A: wa[m,h,d] = sum_e W[m,h,d,e]*a[m,h,e]; block 0 also zeroes sem_sum -------
__global__ void wa_kernel(SixPtr W, SixPtr a, float* __restrict__ wa,
                          float* __restrict__ zero_base, int zero_cnt){
  if (blockIdx.x == 0){
    for (int i = threadIdx.x; i < zero_cnt; i += 256) zero_base[i] = 0.f;
  }
  const int m = blockIdx.x >> 2;
  const int local = ((blockIdx.x & 3) << 8) | threadIdx.x;
  const int h = local >> 8, d = local & 255;
  const float4* wrow = (const float4*)(W.p[m] + (size_t)(h*DD + d)*DD);
  const float4* av   = (const float4*)(a.p[m] + h*DD);
  float acc = 0.f;
  #pragma unroll 8
  for (int e=0;e<64;e++){
    float4 wv = wrow[e], xv = av[e];
    acc += wv.x*xv.x + wv.y*xv.y + wv.z*xv.z + wv.w*xv.w;
  }
  wa[m*1024 + local] = acc;
}

// ---------- Kernel X: fp16 copies of the three feature tables ----------
__global__ void xconv_kernel(SixPtr X, unsigned short* __restrict__ Xh){
  int gid = blockIdx.x*256 + threadIdx.x;   // 0 .. 3*131072-1
  int tb  = gid >> 17;
  int off = gid & 131071;
  float4 v = ((const float4*)X.p[tb])[off];
  ushort4 o = { f2h(v.x), f2h(v.y), f2h(v.z), f2h(v.w) };
  ((ushort4*)(Xh + (size_t)tb*NN*DD))[off] = o;
}

// ---------- Kernel T: out[m][c][r] = f16(in[m][r][c])  (transpose+convert) ----------
__launch_bounds__(256)
__global__ void transconv_kernel(SixPtr in, int R, int C, unsigned short* __restrict__ out){
  __shared__ unsigned short T_s[64][68];
  const int m  = blockIdx.z;
  const int r0 = blockIdx.x*64, c0 = blockIdx.y*64;
  const int t  = threadIdx.x;
  const int rr = t>>4, cc = (t&15)*4;
  const float* src = in.p[m];
  #pragma unroll
  for (int i=0;i<4;i++){
    float4 v = *(const float4*)(src + (size_t)(r0+rr+i*16)*C + c0 + cc);
    T_s[cc+0][rr+i*16]=f2h(v.x);
    T_s[cc+1][rr+i*16]=f2h(v.y);
    T_s[cc+2][rr+i*16]=f2h(v.z);
    T_s[cc+3][rr+i*16]=f2h(v.w);
  }
  __syncthreads();
  const int cr = t>>4, rc = (t&15)*4;
  unsigned short* ob = out + (size_t)m*R*C;
  #pragma unroll
  for (int i=0;i<4;i++){
    ushort4 v = { T_s[cr+i*16][rc+0], T_s[cr+i*16][rc+1],
                  T_s[cr+i*16][rc+2], T_s[cr+i*16][rc+3] };
    *(ushort4*)(ob + (size_t)(c0+cr+i*16)*R + r0 + rc) = v;
  }
}

// ------------- Kernel B: fused gather-max + instance attention (fp16) -------------
template<int P>
__device__ inline void gather_dot(const AllMP& mp, int m, int w, int l, int g, int j,
                                  const int* idx_s, unsigned int (*inst_u)[128],
                                  const h2* wh, float sg, float (*e_s)[HH]){
  // Phase 1: gather-max, lane l owns dims 4l..4l+3 (2 packed h2)
  #pragma unroll
  for (int kk=0; kk<5; kk++){
    const int k = w*5 + kk;
    const int* ib = &idx_s[k*P];
    uint2 r = *(const uint2*)(mp.xs[m][0] + (size_t)ib[0]*DD + 4*l);
    h2 v0 = bch2(r.x), v1 = bch2(r.y);
    #pragma unroll
    for (int p=1;p<P;p++){
      uint2 u = *(const uint2*)(mp.xs[m][p] + (size_t)ib[p]*DD + 4*l);
      v0 = hmax2(v0, bch2(u.x));
      v1 = hmax2(v1, bch2(u.y));
    }
    *(uint2*)&inst_u[k][2*l] = make_uint2(bcu(v0), bcu(v1));
  }
  // Phase 2: logit dots via 16-lane groups (4 heads in parallel)
  #pragma unroll
  for (int kk=0; kk<5; kk++){
    const int k = w*5 + kk;
    float pr = 0.f;
    #pragma unroll
    for (int c=0;c<4;c++){
      uint2 rr = *(const uint2*)&inst_u[k][2*(j+16*c)];
      pr = dot2(bch2(rr.x), wh[2*c+0], pr);
      pr = dot2(bch2(rr.y), wh[2*c+1], pr);
    }
    pr = gsum16(pr);
    if (j==0){
      float logit = pr + sg;
      e_s[k][g] = (logit>0.f) ? logit : 0.2f*logit;
    }
  }
}

__launch_bounds__(256)
__global__ void inst_attn_kernel(AllMP mp, int mp_base, const float* __restrict__ wa_all,
                                 unsigned short* __restrict__ ctxh){
  __shared__ unsigned int inst_u[KK][128];   // 10 KB (fp16 packed)
  __shared__ int   idx_s[KK*5];
  __shared__ float e_s[KK][HH];
  __shared__ float alpha_s[KK][HH];

  const int z = blockIdx.y;
  const int m = mp_base + z;
  const int n = blockIdx.x;
  const int t = threadIdx.x;
  const int w = t >> 6;
  const int l = t & 63;
  const int g = l >> 4;
  const int j = l & 15;
  const int P = mp.P[m];

  const int* __restrict__ gidx = mp.idx[m] + (size_t)n*(KK*P);
  if (l < 5*P) idx_s[w*5*P + l] = gidx[w*5*P + l];

  // wa (head g, 16 dims per lane) as 8 packed h2
  h2 wh[8];
  {
    const float4* wab = (const float4*)(wa_all + m*1024 + g*256);
    float4 w0 = wab[j], w1 = wab[j+16], w2 = wab[j+32], w3 = wab[j+48];
    wh[0]=packh2(w0.x,w0.y); wh[1]=packh2(w0.z,w0.w);
    wh[2]=packh2(w1.x,w1.y); wh[3]=packh2(w1.z,w1.w);
    wh[4]=packh2(w2.x,w2.y); wh[5]=packh2(w2.z,w2.w);
    wh[6]=packh2(w3.x,w3.y); wh[7]=packh2(w3.z,w3.w);
  }

  float sg;
  {
    const unsigned short* xb = mp.xt[m] + (size_t)n*DD;
    float p_ = 0.f;
    #pragma unroll
    for (int c=0;c<4;c++){
      uint2 rr = *(const uint2*)(xb + 4*(j+16*c));
      p_ = dot2(bch2(rr.x), wh[2*c+0], p_);
      p_ = dot2(bch2(rr.y), wh[2*c+1], p_);
    }
    sg = gsum16(p_);
  }

  switch(P){
    case 3: gather_dot<3>(mp,m,w,l,g,j,idx_s,inst_u,wh,sg,e_s); break;
    case 4: gather_dot<4>(mp,m,w,l,g,j,idx_s,inst_u,wh,sg,e_s); break;
    default: gather_dot<5>(mp,m,w,l,g,j,idx_s,inst_u,wh,sg,e_s); break;
  }
  __syncthreads();

  // softmax over K, head w per wave
  {
    float x  = (l<KK) ? e_s[l][w] : -INFINITY;
    float mx = wmax(x);
    float pv = (l<KK) ? expf(x-mx) : 0.f;
    float sm = wsum(pv);
    if (l<KK) alpha_s[l][w] = pv/sm;
  }
  __syncthreads();

  // ctx[h] = sum_k alpha[h,k]*inst[k]; thread t owns column t
  const unsigned short* ih = (const unsigned short*)&inst_u[0][0];
  float c0=0,c1=0,c2=0,c3=0;
  #pragma unroll
  for (int k=0;k<KK;k++){
    float4 al = *(const float4*)&alpha_s[k][0];
    float iv = (float)__builtin_bit_cast(_Float16, ih[k*DD + t]);
    c0 += al.x*iv; c1 += al.y*iv; c2 += al.z*iv; c3 += al.w*iv;
  }
  unsigned short* cb = ctxh + ((size_t)z*NN + n)*1024;
  cb[0*DD+t]=f2h(c0); cb[1*DD+t]=f2h(c1); cb[2*DD+t]=f2h(c2); cb[3*DD+t]=f2h(c3);
}

// ---------- Kernel C: Hmp[m] = (1/H) * ctx_f16 @ W_f16  (MFMA) ----------
__launch_bounds__(256)
__global__ void gemm_kernel(const unsigned short* __restrict__ ctxh,
                            const unsigned short* __restrict__ Wt, int mp_base,
                            float* __restrict__ Hmp){
  __shared__ unsigned short A_s[64][64];
  __shared__ unsigned short B_s[64][64];
  const int z  = blockIdx.z;
  const int m  = mp_base + z;
  const int n0 = blockIdx.x*64, c0 = blockIdx.y*64;
  const int t  = threadIdx.x;
  const int l  = t & 63;
  const int wid  = t >> 6;
  const int wrow = wid & 1, wcol = wid >> 1;
  const unsigned short* Abase = ctxh + (size_t)z*NN*1024;
  const unsigned short* Bbase = Wt   + (size_t)m*256*1024;

  f32x4 acc[2][2] = {};
  const int srow = t>>3, sseg = t&7;

  for (int k0=0; k0<1024; k0+=64){
    #pragma unroll
    for (int r=0;r<2;r++){
      const int row = srow + r*32;
      int4 av = *(const int4*)(Abase + (size_t)(n0+row)*1024 + k0 + sseg*8);
      *(int4*)&A_s[row][(sseg ^ (row&7))*8] = av;
      int4 bv = *(const int4*)(Bbase + (size_t)(c0+row)*1024 + k0 + sseg*8);
      *(int4*)&B_s[row][(sseg ^ (row&7))*8] = bv;
    }
    __syncthreads();
    #pragma unroll
    for (int kf=0;kf<2;kf++){
      half8 a[2], b[2];
      const int s = kf*4 + (l>>4);
      #pragma unroll
      for (int mr=0;mr<2;mr++){
        const int row = wrow*32 + mr*16 + (l&15);
        a[mr] = __builtin_bit_cast(half8, *(const short8*)&A_s[row][(s ^ (row&7))*8]);
      }
      #pragma unroll
      for (int nr=0;nr<2;nr++){
        const int col = wcol*32 + nr*16 + (l&15);
        b[nr] = __builtin_bit_cast(half8, *(const short8*)&B_s[col][(s ^ (col&7))*8]);
      }
      #pragma unroll
      for (int mr=0;mr<2;mr++)
        #pragma unroll
        for (int nr=0;nr<2;nr++)
          acc[mr][nr] = __builtin_amdgcn_mfma_f32_16x16x32_f16(a[mr], b[nr], acc[mr][nr], 0,0,0);
    }
    __syncthreads();
  }
  float* out = Hmp + (size_t)m*NN*DD;
  #pragma unroll
  for (int mr=0;mr<2;mr++){
    const int rbase = n0 + wrow*32 + mr*16 + (l>>4)*4;
    #pragma unroll
    for (int nr=0;nr<2;nr++){
      const int col = c0 + wcol*32 + nr*16 + (l&15);
      #pragma unroll
      for (int r=0;r<4;r++)
        out[(size_t)(rbase+r)*DD + col] = acc[mr][nr][r]*0.25f;
    }
  }
}

// ------- Kernel E (MFMA): sem_sum[m,e] += sum_n tanh(Hmp[m,n,:]·Wm[:,e] + bm[e]) -------
__launch_bounds__(256)
__global__ void sem_kernel(const float* __restrict__ Hmp, SemB sb,
                           float* __restrict__ sem_sum){
  __shared__ unsigned short A_s[64][256];   // 32 KB, swizzled
  __shared__ unsigned short B_s[64][256];   // 32 KB, swizzled
  const int m  = blockIdx.z;
  const int n0 = blockIdx.x*64, c0 = blockIdx.y*64;
  const int t  = threadIdx.x, l = t & 63, wid = t >> 6;
  const int wrow = wid & 1, wcol = wid >> 1;
  const float* Ab = Hmp + (size_t)m*NN*DD;
  const unsigned short* Bb = sb.Wmt[m];

  #pragma unroll
  for (int i=0;i<16;i++){
    int q = t + i*256;
    int row = q>>6, c4 = (q&63)<<2;
    float4 v = *(const float4*)(Ab + (size_t)(n0+row)*DD + c4);
    ushort4 o = { f2h(v.x), f2h(v.y), f2h(v.z), f2h(v.w) };
    int seg8 = c4>>3, half = (c4>>2)&1;
    int segs = (seg8 & 24) | ((seg8&7) ^ (row&7));
    *(ushort4*)((char*)&A_s[0][0] + row*512 + segs*16 + half*8) = o;
  }
  #pragma unroll
  for (int i=0;i<8;i++){
    int q = t + i*256;
    int row = q>>5, seg = q&31;
    int4 v = *(const int4*)(Bb + (size_t)(c0+row)*DD + seg*8);
    int segs = (seg&24) | ((seg&7)^(row&7));
    *(int4*)((char*)&B_s[0][0] + row*512 + segs*16) = v;
  }
  __syncthreads();

  f32x4 acc[2][2] = {};
  #pragma unroll
  for (int kf=0; kf<8; kf++){
    const int s = kf*4 + (l>>4);
    half8 a[2], b[2];
    #pragma unroll
    for (int mr=0;mr<2;mr++){
      int row = wrow*32 + mr*16 + (l&15);
      int ss = (s&24) | ((s&7)^(row&7));
      a[mr] = __builtin_bit_cast(half8, *(const short8*)((const char*)&A_s[0][0] + row*512 + ss*16));
    }
    #pragma unroll
    for (int nr=0;nr<2;nr++){
      int row = wcol*32 + nr*16 + (l&15);
      int ss = (s&24) | ((s&7)^(row&7));
      b[nr] = __builtin_bit_cast(half8, *(const short8*)((const char*)&B_s[0][0] + row*512 + ss*16));
    }
    #pragma unroll
    for (int mr=0;mr<2;mr++)
      #pragma unroll
      for (int nr=0;nr<2;nr++)
        acc[mr][nr] = __builtin_amdgcn_mfma_f32_16x16x32_f16(a[mr], b[nr], acc[mr][nr], 0,0,0);
  }

  #pragma unroll
  for (int nr=0;nr<2;nr++){
    const int col = c0 + wcol*32 + nr*16 + (l&15);
    float b = sb.bm[m][col];
    float sv = 0.f;
    #pragma unroll
    for (int mr=0;mr<2;mr++)
      #pragma unroll
      for (int r=0;r<4;r++)
        sv += tanhf(acc[mr][nr][r] + b);
    sv += __shfl_xor(sv,16);
    sv += __shfl_xor(sv,32);
    if (l < 16) atomicAdd(&sem_sum[m*DD + col], sv);
  }
}

// ---------------- Kernel F: beta softmax per node type ----------------
struct TypeInfo { const float* qm; float* sem; int P; int beta_off; };
__global__ void beta_kernel(TypeInfo ti0, TypeInfo ti1, TypeInfo ti2,
                            float* __restrict__ out_beta, float* __restrict__ beta_ws){
  TypeInfo ti = (blockIdx.x==0) ? ti0 : (blockIdx.x==1) ? ti1 : ti2;
  const int t = threadIdx.x;
  __shared__ float red[4];
  __shared__ float logits[3];
  float q = ti.qm[t];
  for (int p=0;p<ti.P;p++){
    float sm = ti.sem[p*DD + t] * (1.0f/NN);
    float v = tanhf(sm)*q;
    v = wsum(v);
    if ((t&63)==0) red[t>>6] = v;
    __syncthreads();
    if (t==0) logits[p] = red[0]+red[1]+red[2]+red[3];
    __syncthreads();
  }
  if (t==0){
    float mx = -INFINITY;
    for (int p=0;p<ti.P;p++) mx = fmaxf(mx, logits[p]);
    float s = 0.f, e[3];
    for (int p=0;p<ti.P;p++){ e[p] = expf(logits[p]-mx); s += e[p]; }
    for (int p=0;p<ti.P;p++){
      float b = e[p]/s;
      out_beta[ti.beta_off + p] = b;
      beta_ws[blockIdx.x*3 + p] = b;
    }
  }
}

// ---------------- Kernel G: out[n,d] = sum_p beta[p]*H_p[n,d] ----------------
__global__ void combine_kernel(const float* __restrict__ Hmp,
                               const float* __restrict__ beta_ws,
                               float* __restrict__ out){
  int type = blockIdx.y;
  int start = (type==0) ? 0 : (type==1) ? 2 : 5;
  int P = (type==0) ? 2 : (type==1) ? 3 : 1;
  size_t i = (size_t)blockIdx.x*blockDim.x + threadIdx.x;
  const float* base = Hmp + (size_t)start*NN*DD;
  float acc = 0.f;
  for (int p=0;p<P;p++) acc += beta_ws[type*3+p]*base[(size_t)p*NN*DD + i];
  out[(size_t)type*NN*DD + i] = acc;
}

extern "C" void kernel_launch(void* const* d_in, const int* in_sizes, int n_in,
                              void* d_out, int out_size, void* d_ws, size_t ws_size,
                              hipStream_t stream) {
  SixPtr Xp; Xp.p[0]=(const float*)d_in[0]; Xp.p[1]=(const float*)d_in[1]; Xp.p[2]=(const float*)d_in[2];
  for (int i=3;i<6;i++) Xp.p[i]=Xp.p[0];

  SixPtr Wl, al;
  for (int m=0;m<6;m++){ Wl.p[m] = (const float*)d_in[9+2*m]; al.p[m] = (const float*)d_in[10+2*m]; }
  const float* Wm_[3]; const float* bm_[3]; const float* qm_[3];
  for (int tt=0;tt<3;tt++){
    Wm_[tt] = (const float*)d_in[21+3*tt];
    bm_[tt] = (const float*)d_in[22+3*tt];
    qm_[tt] = (const float*)d_in[23+3*tt];
  }
  SixPtr Wm3; for (int i=0;i<6;i++) Wm3.p[i] = Wm_[i<3?i:0];

  // ---- workspace layout ----
  char* ws = (char*)d_ws;
  float* wa_all  = (float*)ws;                               ws += 6*1024*4;
  float* sem_sum = (float*)ws;                               ws += 6*DD*4;
  float* beta_ws = (float*)ws;                               ws += 16*4;
  float* Hmp     = (float*)ws;                               ws += (size_t)6*NN*DD*4;
  unsigned short* Wt   = (unsigned short*)ws;                ws += (size_t)6*256*1024*2;
  unsigned short* Wmt  = (unsigned short*)ws;                ws += (size_t)3*256*256*2;
  unsigned short* Xh   = (unsigned short*)ws;                ws += (size_t)3*NN*DD*2;
  unsigned short* ctxh = (unsigned short*)ws;                // up to 6*NN*1024*2

  const size_t fixed = (size_t)(ws - (char*)d_ws);
  const size_t per_mp = (size_t)NN*1024*2;
  const int B = (ws_size >= fixed + 6*per_mp) ? 6 : 3;   // 3 proven to fit in prior rounds

  AllMP mp;
  for (int m=0;m<6;m++) mp.idx[m] = (const int*)d_in[3+m];
  const int P_[6] = {3,5,3,3,4,5};
  for (int m=0;m<6;m++) mp.P[m] = P_[m];
  const int xt_t[6] = {0,0,1,1,1,2};
  const int gp_t[6][5] = {
    {0,1,0,0,0}, {0,1,2,1,0}, {1,2,1,1,1},
    {1,0,1,1,1}, {1,0,0,1,1}, {2,1,0,1,2}};
  for (int m=0;m<6;m++){
    mp.xt[m] = Xh + (size_t)xt_t[m]*NN*DD;
    for (int p=0;p<5;p++) mp.xs[m][p] = Xh + (size_t)gp_t[m][p]*NN*DD;
  }

  SemB sb;
  const int type_of[6] = {0,0,1,1,1,2};
  for (int m=0;m<6;m++){
    sb.Wmt[m] = Wmt + (size_t)type_of[m]*256*256;
    sb.bm[m]  = bm_[type_of[m]];
  }

  wa_kernel<<<dim3(24),dim3(256),0,stream>>>(Wl, al, wa_all, sem_sum, 6*DD+16);
  xconv_kernel<<<dim3(1536),dim3(256),0,stream>>>(Xp, Xh);
  transconv_kernel<<<dim3(16,4,6),dim3(256),0,stream>>>(Wl, 1024, 256, Wt);
  transconv_kernel<<<dim3(4,4,3),dim3(256),0,stream>>>(Wm3, 256, 256, Wmt);

  for (int g=0; g<6; g+=B){
    int nb = (6-g < B) ? (6-g) : B;
    inst_attn_kernel<<<dim3(NN,nb),dim3(256),0,stream>>>(mp, g, wa_all, ctxh);
    gemm_kernel<<<dim3(32,4,nb),dim3(256),0,stream>>>(ctxh, Wt, g, Hmp);
  }

  sem_kernel<<<dim3(32,4,6),dim3(256),0,stream>>>(Hmp, sb, sem_sum);

  float* out = (float*)d_out;
  TypeInfo t0{qm_[0], sem_sum + 0*DD, 2, 0};
  TypeInfo t1{qm_[1], sem_sum + 2*DD, 3, 2};
  TypeInfo t2{qm_[2], sem_sum + 5*DD, 1, 5};
  beta_kernel<<<dim3(3),dim3(256),0,stream>>>(t0, t1, t2, out + (size_t)3*NN*DD, beta_ws);

  combine_kernel<<<dim3((NN*DD)/256,3),dim3(256),0,stream>>>(Hmp, beta_ws, out);
}

// Round 6
// 104.032 us; speedup vs baseline: 7.4227x; 1.2689x over previous
//
#include <hip/hip_runtime.h>
#include <math.h>

#define NN 2048
#define DD 256
#define KK 20
#define HH 4

typedef short short8 __attribute__((ext_vector_type(8)));
typedef float f32x4  __attribute__((ext_vector_type(4)));
typedef _Float16 half8 __attribute__((ext_vector_type(8)));
typedef _Float16 h2    __attribute__((ext_vector_type(2)));

#if defined(__has_builtin)
#  if __has_builtin(__builtin_amdgcn_fdot2)
#    define HAS_FDOT2 1
#  else
#    define HAS_FDOT2 0
#  endif
#else
#  define HAS_FDOT2 0
#endif

struct AllMP  { const unsigned short* xs[6][5]; const int* idx[6]; const unsigned short* xt[6]; int P[6]; };
struct SixPtr { const float* p[6]; };
struct SemB   { const unsigned short* Wmt[6]; const float* bm[6]; };

__device__ inline float wsum(float v){
  #pragma unroll
  for (int o=32;o;o>>=1) v += __shfl_xor(v,o);
  return v;
}
__device__ inline float wmax(float v){
  #pragma unroll
  for (int o=32;o;o>>=1) v = fmaxf(v,__shfl_xor(v,o));
  return v;
}
__device__ inline float gsum16(float v){
  #pragma unroll
  for (int o=8;o;o>>=1) v += __shfl_xor(v,o);
  return v;
}
__device__ inline unsigned short f2h(float x){
  return __builtin_bit_cast(unsigned short, (_Float16)x);
}
__device__ inline float h2f(unsigned short u){
  return (float)__builtin_bit_cast(_Float16, u);
}
__device__ inline h2 bch2(unsigned int u){ return __builtin_bit_cast(h2, u); }
__device__ inline unsigned int bcu(h2 v){ return __builtin_bit_cast(unsigned int, v); }
__device__ inline h2 packh2(float a, float b){ h2 r; r[0]=(_Float16)a; r[1]=(_Float16)b; return r; }
__device__ inline h2 hmax2(h2 a, h2 b){
  unsigned int d, ua = bcu(a), ub = bcu(b);
  asm("v_pk_max_f16 %0, %1, %2" : "=v"(d) : "v"(ua), "v"(ub));
  return bch2(d);
}
__device__ inline float dot2(h2 a, h2 b, float c){
#if HAS_FDOT2
  return __builtin_amdgcn_fdot2(a, b, c, false);
#else
  return c + (float)a[0]*(float)b[0] + (float)a[1]*(float)b[1];
#endif
}
// async global->LDS, 16B per lane; lds dest = base + 16*lane (wave-uniform base)
__device__ inline void glds16(const void* g, void* l){
  __builtin_amdgcn_global_load_lds(
    (const __attribute__((address_space(1))) unsigned int*)g,
    (__attribute__((address_space(3))) unsigned int*)l, 16, 0, 0);
}

// ---------------- Kernel P: fused prep (wa | xconv | Wt transpose | Wmt transpose) ----------------
// All transposed fp16 weight tables are stored PRE-SWIZZLED: element [row][col] at
// col ^ ((row&7)<<3)  (XOR on bits 3..5 of the column index) -> linear LDS staging later.
__launch_bounds__(256)
__global__ void prep_kernel(SixPtr W, SixPtr a, SixPtr Xp, SixPtr Wm3,
                            float* __restrict__ wa, unsigned short* __restrict__ Xh,
                            unsigned short* __restrict__ Wt, unsigned short* __restrict__ Wmt,
                            float* __restrict__ zero_base, int zero_cnt){
  __shared__ unsigned short T_s[64][68];
  int b = blockIdx.x;
  const int t = threadIdx.x;

  if (b < 24){                       // ---- wa[m,h,d] = sum_e W[m,h,d,e]*a[m,h,e]
    if (b == 0){
      for (int i=t;i<zero_cnt;i+=256) zero_base[i] = 0.f;
    }
    const int m = b >> 2;
    const int local = ((b & 3) << 8) | t;
    const int h = local >> 8, d = local & 255;
    const float4* wrow = (const float4*)(W.p[m] + (size_t)(h*DD + d)*DD);
    const float4* av   = (const float4*)(a.p[m] + h*DD);
    float acc = 0.f;
    #pragma unroll 8
    for (int e=0;e<64;e++){
      float4 wv = wrow[e], xv = av[e];
      acc += wv.x*xv.x + wv.y*xv.y + wv.z*xv.z + wv.w*xv.w;
    }
    wa[m*1024 + local] = acc;
    return;
  }
  b -= 24;
  if (b < 1536){                     // ---- Xh: fp16 copies of feature tables (NOT swizzled)
    int gid = b*256 + t;
    int tb  = gid >> 17;
    int off = gid & 131071;
    float4 v = ((const float4*)Xp.p[tb])[off];
    ushort4 o = { f2h(v.x), f2h(v.y), f2h(v.z), f2h(v.w) };
    ((ushort4*)(Xh + (size_t)tb*NN*DD))[off] = o;
    return;
  }
  b -= 1536;
  const float* src; unsigned short* ob; int R, C, r0, c0;
  if (b < 384){                      // ---- Wt[m][c][q] = f16(W[m][q][c]), swizzled
    int m = b/64, rem = b%64;
    src = W.p[m]; ob = Wt + (size_t)m*256*1024;
    R = 1024; C = 256; r0 = (rem>>2)*64; c0 = (rem&3)*64;
  } else {                           // ---- Wmt[tt][e][d] = f16(Wm[tt][d][e]), swizzled
    int bb = b-384;
    int m = bb/16, rem = bb%16;
    src = Wm3.p[m]; ob = Wmt + (size_t)m*256*256;
    R = 256; C = 256; r0 = (rem>>2)*64; c0 = (rem&3)*64;
  }
  {
    const int rr = t>>4, cc = (t&15)*4;
    #pragma unroll
    for (int i=0;i<4;i++){
      float4 v = *(const float4*)(src + (size_t)(r0+rr+i*16)*C + c0 + cc);
      T_s[cc+0][rr+i*16]=f2h(v.x);
      T_s[cc+1][rr+i*16]=f2h(v.y);
      T_s[cc+2][rr+i*16]=f2h(v.z);
      T_s[cc+3][rr+i*16]=f2h(v.w);
    }
    __syncthreads();
    const int cr = t>>4, rc = (t&15)*4;
    #pragma unroll
    for (int i=0;i<4;i++){
      int c = c0 + cr + i*16;
      ushort4 v = { T_s[cr+i*16][rc+0], T_s[cr+i*16][rc+1],
                    T_s[cr+i*16][rc+2], T_s[cr+i*16][rc+3] };
      int col = (r0 + rc) ^ ((c&7)<<3);   // pre-swizzle (bits 3..5)
      *(ushort4*)(ob + (size_t)c*R + col) = v;
    }
  }
}

// ------------- Kernel B: fused gather-max + instance attention (fp16, scalar idx) -------------
template<int P>
__device__ inline void gather_dot(const AllMP& mp, int m, int wu, int l, int g, int j,
                                  const int* __restrict__ gidx, unsigned int (*inst_u)[128],
                                  const h2* wh, float sg, float (*e_s)[HH]){
  #pragma unroll
  for (int kk=0; kk<5; kk++){
    const int k = wu*5 + kk;
    // indices are wave-uniform; wu is SGPR -> these become scalar loads
    const unsigned short* rp[P];
    #pragma unroll
    for (int p=0;p<P;p++){
      int id = gidx[k*P + p];
      rp[p] = mp.xs[m][p] + (size_t)id*DD;
    }
    uint2 r = *(const uint2*)(rp[0] + 4*l);
    h2 v0 = bch2(r.x), v1 = bch2(r.y);
    #pragma unroll
    for (int p=1;p<P;p++){
      uint2 u = *(const uint2*)(rp[p] + 4*l);
      v0 = hmax2(v0, bch2(u.x));
      v1 = hmax2(v1, bch2(u.y));
    }
    *(uint2*)&inst_u[k][2*l] = make_uint2(bcu(v0), bcu(v1));
  }
  #pragma unroll
  for (int kk=0; kk<5; kk++){
    const int k = wu*5 + kk;
    float pr = 0.f;
    #pragma unroll
    for (int c=0;c<4;c++){
      uint2 rr = *(const uint2*)&inst_u[k][2*(j+16*c)];
      pr = dot2(bch2(rr.x), wh[2*c+0], pr);
      pr = dot2(bch2(rr.y), wh[2*c+1], pr);
    }
    pr = gsum16(pr);
    if (j==0){
      float logit = pr + sg;
      e_s[k][g] = (logit>0.f) ? logit : 0.2f*logit;
    }
  }
}

__launch_bounds__(256)
__global__ void inst_attn_kernel(AllMP mp, const float* __restrict__ wa_all,
                                 unsigned short* __restrict__ ctxh){
  __shared__ unsigned int inst_u[KK][128];   // 10 KB fp16-packed
  __shared__ float e_s[KK][HH];
  __shared__ float alpha_s[KK][HH];

  const int m = blockIdx.y;
  const int n = blockIdx.x;
  const int t = threadIdx.x;
  const int l = t & 63;
  const int wu = __builtin_amdgcn_readfirstlane(t >> 6);  // SGPR wave id
  const int g = l >> 4;
  const int j = l & 15;
  const int P = mp.P[m];
  const int* __restrict__ gidx = mp.idx[m] + (size_t)n*(KK*P);

  h2 wh[8];
  {
    const float4* wab = (const float4*)(wa_all + m*1024 + g*256);
    float4 w0 = wab[j], w1 = wab[j+16], w2 = wab[j+32], w3 = wab[j+48];
    wh[0]=packh2(w0.x,w0.y); wh[1]=packh2(w0.z,w0.w);
    wh[2]=packh2(w1.x,w1.y); wh[3]=packh2(w1.z,w1.w);
    wh[4]=packh2(w2.x,w2.y); wh[5]=packh2(w2.z,w2.w);
    wh[6]=packh2(w3.x,w3.y); wh[7]=packh2(w3.z,w3.w);
  }

  float sg;
  {
    const unsigned short* xb = mp.xt[m] + (size_t)n*DD;
    float p_ = 0.f;
    #pragma unroll
    for (int c=0;c<4;c++){
      uint2 rr = *(const uint2*)(xb + 4*(j+16*c));
      p_ = dot2(bch2(rr.x), wh[2*c+0], p_);
      p_ = dot2(bch2(rr.y), wh[2*c+1], p_);
    }
    sg = gsum16(p_);
  }

  switch(P){
    case 3: gather_dot<3>(mp,m,wu,l,g,j,gidx,inst_u,wh,sg,e_s); break;
    case 4: gather_dot<4>(mp,m,wu,l,g,j,gidx,inst_u,wh,sg,e_s); break;
    default: gather_dot<5>(mp,m,wu,l,g,j,gidx,inst_u,wh,sg,e_s); break;
  }
  __syncthreads();

  {
    float x  = (l<KK) ? e_s[l][wu] : -INFINITY;
    float mx = wmax(x);
    float pv = (l<KK) ? expf(x-mx) : 0.f;
    float sm = wsum(pv);
    if (l<KK) alpha_s[l][wu] = pv/sm;
  }
  __syncthreads();

  // ctx[h] = sum_k alpha[h,k]*inst[k]; thread t owns col t; PRE-SWIZZLED store
  const unsigned short* ih = (const unsigned short*)&inst_u[0][0];
  float c0=0,c1=0,c2=0,c3=0;
  #pragma unroll
  for (int k=0;k<KK;k++){
    float4 al = *(const float4*)&alpha_s[k][0];
    float iv = h2f(ih[k*DD + t]);
    c0 += al.x*iv; c1 += al.y*iv; c2 += al.z*iv; c3 += al.w*iv;
  }
  unsigned short* cb = ctxh + ((size_t)m*NN + n)*1024;
  const int ts = t ^ ((n&7)<<3);
  cb[0*DD+ts]=f2h(c0); cb[1*DD+ts]=f2h(c1); cb[2*DD+ts]=f2h(c2); cb[3*DD+ts]=f2h(c3);
}

// ---------- Kernel C: Hmp[m] = (1/H) * ctx_f16 @ W_f16 (MFMA, global_load_lds staging) ----------
// Sources pre-swizzled -> linear LDS dest; reads apply the XOR. Output fp16, pre-swizzled.
__launch_bounds__(256)
__global__ void gemm_kernel(const unsigned short* __restrict__ ctxh,
                            const unsigned short* __restrict__ Wt,
                            unsigned short* __restrict__ Hmp){
  __shared__ unsigned short A_s[64][64];
  __shared__ unsigned short B_s[64][64];
  const int m  = blockIdx.z;
  const int n0 = blockIdx.x*64, c0 = blockIdx.y*64;
  const int t  = threadIdx.x;
  const int l  = t & 63;
  const int wid  = t >> 6;
  const int wrow = wid & 1, wcol = wid >> 1;
  const unsigned short* Abase = ctxh + (size_t)m*NN*1024;
  const unsigned short* Bbase = Wt   + (size_t)m*256*1024;

  f32x4 acc[2][2] = {};
  const int row8 = l>>3, seg = l&7;

  for (int k0=0; k0<1024; k0+=64){
    #pragma unroll
    for (int i=0;i<2;i++){
      const int r = wid*16 + i*8;
      glds16(Abase + (size_t)(n0+r+row8)*1024 + k0 + seg*8, &A_s[r][0]);
      glds16(Bbase + (size_t)(c0+r+row8)*1024 + k0 + seg*8, &B_s[r][0]);
    }
    __syncthreads();
    #pragma unroll
    for (int kf=0;kf<2;kf++){
      half8 a[2], b[2];
      const int s = kf*4 + (l>>4);
      #pragma unroll
      for (int mr=0;mr<2;mr++){
        const int row = wrow*32 + mr*16 + (l&15);
        a[mr] = __builtin_bit_cast(half8, *(const short8*)&A_s[row][(s ^ (row&7))*8]);
      }
      #pragma unroll
      for (int nr=0;nr<2;nr++){
        const int col = wcol*32 + nr*16 + (l&15);
        b[nr] = __builtin_bit_cast(half8, *(const short8*)&B_s[col][(s ^ (col&7))*8]);
      }
      #pragma unroll
      for (int mr=0;mr<2;mr++)
        #pragma unroll
        for (int nr=0;nr<2;nr++)
          acc[mr][nr] = __builtin_amdgcn_mfma_f32_16x16x32_f16(a[mr], b[nr], acc[mr][nr], 0,0,0);
    }
    __syncthreads();
  }
  unsigned short* out = Hmp + (size_t)m*NN*DD;
  #pragma unroll
  for (int mr=0;mr<2;mr++){
    const int rbase = n0 + wrow*32 + mr*16 + (l>>4)*4;
    #pragma unroll
    for (int nr=0;nr<2;nr++){
      const int col = c0 + wcol*32 + nr*16 + (l&15);
      #pragma unroll
      for (int r=0;r<4;r++){
        const int rw = rbase + r;
        out[(size_t)rw*DD + (col ^ ((rw&7)<<3))] = f2h(acc[mr][nr][r]*0.25f);
      }
    }
  }
}

// ------- Kernel E (MFMA): sem_sum[m,e] += sum_n tanh(Hmp[m,n,:]·Wm[:,e] + bm[e]) -------
__launch_bounds__(256)
__global__ void sem_kernel(const unsigned short* __restrict__ Hmp, SemB sb,
                           float* __restrict__ sem_sum){
  __shared__ unsigned short A_s[64][256];   // 32 KB
  __shared__ unsigned short B_s[64][256];   // 32 KB
  const int m  = blockIdx.z;
  const int n0 = blockIdx.x*64, c0 = blockIdx.y*64;
  const int t  = threadIdx.x, l = t & 63, wid = t >> 6;
  const int wrow = wid & 1, wcol = wid >> 1;
  const unsigned short* Ab = Hmp + (size_t)m*NN*DD;
  const unsigned short* Bb = sb.Wmt[m];

  const int row2 = l>>5, seg = l&31;
  #pragma unroll
  for (int i=0;i<8;i++){
    const int r = wid*16 + i*2;
    glds16(Ab + (size_t)(n0+r+row2)*DD + seg*8, &A_s[r][0]);
    glds16(Bb + (size_t)(c0+r+row2)*DD + seg*8, &B_s[r][0]);
  }
  __syncthreads();

  f32x4 acc[2][2] = {};
  #pragma unroll
  for (int kf=0; kf<8; kf++){
    const int s = kf*4 + (l>>4);
    half8 a[2], b[2];
    #pragma unroll
    for (int mr=0;mr<2;mr++){
      int row = wrow*32 + mr*16 + (l&15);
      int ss = (s&24) | ((s&7)^(row&7));
      a[mr] = __builtin_bit_cast(half8, *(const short8*)((const char*)&A_s[0][0] + row*512 + ss*16));
    }
    #pragma unroll
    for (int nr=0;nr<2;nr++){
      int row = wcol*32 + nr*16 + (l&15);
      int ss = (s&24) | ((s&7)^(row&7));
      b[nr] = __builtin_bit_cast(half8, *(const short8*)((const char*)&B_s[0][0] + row*512 + ss*16));
    }
    #pragma unroll
    for (int mr=0;mr<2;mr++)
      #pragma unroll
      for (int nr=0;nr<2;nr++)
        acc[mr][nr] = __builtin_amdgcn_mfma_f32_16x16x32_f16(a[mr], b[nr], acc[mr][nr], 0,0,0);
  }

  #pragma unroll
  for (int nr=0;nr<2;nr++){
    const int col = c0 + wcol*32 + nr*16 + (l&15);
    float b = sb.bm[m][col];
    float sv = 0.f;
    #pragma unroll
    for (int mr=0;mr<2;mr++)
      #pragma unroll
      for (int r=0;r<4;r++)
        sv += tanhf(acc[mr][nr][r] + b);
    sv += __shfl_xor(sv,16);
    sv += __shfl_xor(sv,32);
    if (l < 16) atomicAdd(&sem_sum[m*DD + col], sv);
  }
}

// ---------------- Kernel F: beta softmax per node type ----------------
struct TypeInfo { const float* qm; float* sem; int P; int beta_off; };
__global__ void beta_kernel(TypeInfo ti0, TypeInfo ti1, TypeInfo ti2,
                            float* __restrict__ out_beta, float* __restrict__ beta_ws){
  TypeInfo ti = (blockIdx.x==0) ? ti0 : (blockIdx.x==1) ? ti1 : ti2;
  const int t = threadIdx.x;
  __shared__ float red[4];
  __shared__ float logits[3];
  float q = ti.qm[t];
  for (int p=0;p<ti.P;p++){
    float sm = ti.sem[p*DD + t] * (1.0f/NN);
    float v = tanhf(sm)*q;
    v = wsum(v);
    if ((t&63)==0) red[t>>6] = v;
    __syncthreads();
    if (t==0) logits[p] = red[0]+red[1]+red[2]+red[3];
    __syncthreads();
  }
  if (t==0){
    float mx = -INFINITY;
    for (int p=0;p<ti.P;p++) mx = fmaxf(mx, logits[p]);
    float s = 0.f, e[3];
    for (int p=0;p<ti.P;p++){ e[p] = expf(logits[p]-mx); s += e[p]; }
    for (int p=0;p<ti.P;p++){
      float b = e[p]/s;
      out_beta[ti.beta_off + p] = b;
      beta_ws[blockIdx.x*3 + p] = b;
    }
  }
}

// ------------- Kernel G: out[type][n][d] = sum_p beta[p]*Hmp_swz[p][n][d^swz] -------------
__global__ void combine_kernel(const unsigned short* __restrict__ Hmp,
                               const float* __restrict__ beta_ws,
                               float* __restrict__ out){
  const int type = blockIdx.y;
  const int start = (type==0) ? 0 : (type==1) ? 2 : 5;
  const int P = (type==0) ? 2 : (type==1) ? 3 : 1;
  const int n = blockIdx.x;
  const int d = threadIdx.x;
  const int ds = d ^ ((n&7)<<3);
  const unsigned short* base = Hmp + ((size_t)start*NN + n)*DD + ds;
  float acc = 0.f;
  for (int p=0;p<P;p++) acc += beta_ws[type*3+p]*h2f(base[(size_t)p*NN*DD]);
  out[((size_t)type*NN + n)*DD + d] = acc;
}

extern "C" void kernel_launch(void* const* d_in, const int* in_sizes, int n_in,
                              void* d_out, int out_size, void* d_ws, size_t ws_size,
                              hipStream_t stream) {
  SixPtr Xp; Xp.p[0]=(const float*)d_in[0]; Xp.p[1]=(const float*)d_in[1]; Xp.p[2]=(const float*)d_in[2];
  for (int i=3;i<6;i++) Xp.p[i]=Xp.p[0];

  SixPtr Wl, al;
  for (int m=0;m<6;m++){ Wl.p[m] = (const float*)d_in[9+2*m]; al.p[m] = (const float*)d_in[10+2*m]; }
  const float* Wm_[3]; const float* bm_[3]; const float* qm_[3];
  for (int tt=0;tt<3;tt++){
    Wm_[tt] = (const float*)d_in[21+3*tt];
    bm_[tt] = (const float*)d_in[22+3*tt];
    qm_[tt] = (const float*)d_in[23+3*tt];
  }
  SixPtr Wm3; for (int i=0;i<6;i++) Wm3.p[i] = Wm_[i<3?i:0];

  // ---- workspace layout (~46 MB; ws_size = 256 MiB per round-4 poison fill) ----
  char* ws = (char*)d_ws;
  float* wa_all  = (float*)ws;                               ws += 6*1024*4;
  float* sem_sum = (float*)ws;                               ws += 6*DD*4;
  float* beta_ws = (float*)ws;                               ws += 16*4;
  unsigned short* Hmp  = (unsigned short*)ws;                ws += (size_t)6*NN*DD*2;
  unsigned short* Wt   = (unsigned short*)ws;                ws += (size_t)6*256*1024*2;
  unsigned short* Wmt  = (unsigned short*)ws;                ws += (size_t)3*256*256*2;
  unsigned short* Xh   = (unsigned short*)ws;                ws += (size_t)3*NN*DD*2;
  unsigned short* ctxh = (unsigned short*)ws;                // 6*NN*1024*2 = 24 MB

  AllMP mp;
  for (int m=0;m<6;m++) mp.idx[m] = (const int*)d_in[3+m];
  const int P_[6] = {3,5,3,3,4,5};
  for (int m=0;m<6;m++) mp.P[m] = P_[m];
  const int xt_t[6] = {0,0,1,1,1,2};
  const int gp_t[6][5] = {
    {0,1,0,0,0}, {0,1,2,1,0}, {1,2,1,1,1},
    {1,0,1,1,1}, {1,0,0,1,1}, {2,1,0,1,2}};
  for (int m=0;m<6;m++){
    mp.xt[m] = Xh + (size_t)xt_t[m]*NN*DD;
    for (int p=0;p<5;p++) mp.xs[m][p] = Xh + (size_t)gp_t[m][p]*NN*DD;
  }

  SemB sb;
  const int type_of[6] = {0,0,1,1,1,2};
  for (int m=0;m<6;m++){
    sb.Wmt[m] = Wmt + (size_t)type_of[m]*256*256;
    sb.bm[m]  = bm_[type_of[m]];
  }

  prep_kernel<<<dim3(24+1536+384+48),dim3(256),0,stream>>>(
      Wl, al, Xp, Wm3, wa_all, Xh, Wt, Wmt, sem_sum, 6*DD+16);

  inst_attn_kernel<<<dim3(NN,6),dim3(256),0,stream>>>(mp, wa_all, ctxh);
  gemm_kernel<<<dim3(32,4,6),dim3(256),0,stream>>>(ctxh, Wt, Hmp);
  sem_kernel<<<dim3(32,4,6),dim3(256),0,stream>>>(Hmp, sb, sem_sum);

  float* out = (float*)d_out;
  TypeInfo t0{qm_[0], sem_sum + 0*DD, 2, 0};
  TypeInfo t1{qm_[1], sem_sum + 2*DD, 3, 2};
  TypeInfo t2{qm_[2], sem_sum + 5*DD, 1, 5};
  beta_kernel<<<dim3(3),dim3(256),0,stream>>>(t0, t1, t2, out + (size_t)3*NN*DD, beta_ws);

  combine_kernel<<<dim3(NN,3),dim3(256),0,stream>>>(Hmp, beta_ws, out);
}

// Round 7
// 91.213 us; speedup vs baseline: 8.4659x; 1.1405x over previous
//
#include <hip/hip_runtime.h>
#include <math.h>

#define NN 2048
#define DD 256
#define KK 20
#define HH 4

typedef short short8 __attribute__((ext_vector_type(8)));
typedef float f32x4  __attribute__((ext_vector_type(4)));
typedef _Float16 half8 __attribute__((ext_vector_type(8)));
typedef _Float16 h2    __attribute__((ext_vector_type(2)));

#if defined(__has_builtin)
#  if __has_builtin(__builtin_amdgcn_fdot2)
#    define HAS_FDOT2 1
#  else
#    define HAS_FDOT2 0
#  endif
#else
#  define HAS_FDOT2 0
#endif

struct AllMP  { const unsigned short* xs[6][5]; const int* idx[6]; const unsigned short* xt[6]; int P[6]; };
struct SixPtr { const float* p[6]; };
struct SemB   { const unsigned short* Wmt[6]; const float* bm[6]; };

__device__ inline float wsum(float v){
  #pragma unroll
  for (int o=32;o;o>>=1) v += __shfl_xor(v,o);
  return v;
}
__device__ inline float gsum16(float v){
  #pragma unroll
  for (int o=8;o;o>>=1) v += __shfl_xor(v,o);
  return v;
}
__device__ inline unsigned short f2h(float x){
  return __builtin_bit_cast(unsigned short, (_Float16)x);
}
__device__ inline float h2f(unsigned short u){
  return (float)__builtin_bit_cast(_Float16, u);
}
__device__ inline h2 bch2(unsigned int u){ return __builtin_bit_cast(h2, u); }
__device__ inline unsigned int bcu(h2 v){ return __builtin_bit_cast(unsigned int, v); }
__device__ inline h2 packh2(float a, float b){ h2 r; r[0]=(_Float16)a; r[1]=(_Float16)b; return r; }
__device__ inline h2 hmax2(h2 a, h2 b){
  unsigned int d, ua = bcu(a), ub = bcu(b);
  asm("v_pk_max_f16 %0, %1, %2" : "=v"(d) : "v"(ua), "v"(ub));
  return bch2(d);
}
__device__ inline float dot2(h2 a, h2 b, float c){
#if HAS_FDOT2
  return __builtin_amdgcn_fdot2(a, b, c, false);
#else
  return c + (float)a[0]*(float)b[0] + (float)a[1]*(float)b[1];
#endif
}
// async global->LDS, 16B per lane; lds dest = base + 16*lane (wave-uniform base)
__device__ inline void glds16(const void* g, void* l){
  __builtin_amdgcn_global_load_lds(
    (const __attribute__((address_space(1))) unsigned int*)g,
    (__attribute__((address_space(3))) unsigned int*)l, 16, 0, 0);
}

// ---------------- Kernel P: fused prep (wa | xconv | Wt transpose | Wmt transpose) ----------------
// All transposed fp16 weight tables stored PRE-SWIZZLED: element [row][col] at
// col ^ ((row&7)<<3) -> linear LDS staging later.
__launch_bounds__(256)
__global__ void prep_kernel(SixPtr W, SixPtr a, SixPtr Xp, SixPtr Wm3,
                            float* __restrict__ wa, unsigned short* __restrict__ Xh,
                            unsigned short* __restrict__ Wt, unsigned short* __restrict__ Wmt,
                            float* __restrict__ zero_base, int zero_cnt){
  __shared__ unsigned short T_s[64][68];
  int b = blockIdx.x;
  const int t = threadIdx.x;

  if (b < 24){                       // ---- wa[m,h,d] = sum_e W[m,h,d,e]*a[m,h,e]
    if (b == 0){
      for (int i=t;i<zero_cnt;i+=256) zero_base[i] = 0.f;
    }
    const int m = b >> 2;
    const int local = ((b & 3) << 8) | t;
    const int h = local >> 8, d = local & 255;
    const float4* wrow = (const float4*)(W.p[m] + (size_t)(h*DD + d)*DD);
    const float4* av   = (const float4*)(a.p[m] + h*DD);
    float acc = 0.f;
    #pragma unroll 8
    for (int e=0;e<64;e++){
      float4 wv = wrow[e], xv = av[e];
      acc += wv.x*xv.x + wv.y*xv.y + wv.z*xv.z + wv.w*xv.w;
    }
    wa[m*1024 + local] = acc;
    return;
  }
  b -= 24;
  if (b < 1536){                     // ---- Xh: fp16 copies of feature tables
    int gid = b*256 + t;
    int tb  = gid >> 17;
    int off = gid & 131071;
    float4 v = ((const float4*)Xp.p[tb])[off];
    ushort4 o = { f2h(v.x), f2h(v.y), f2h(v.z), f2h(v.w) };
    ((ushort4*)(Xh + (size_t)tb*NN*DD))[off] = o;
    return;
  }
  b -= 1536;
  const float* src; unsigned short* ob; int R, C, r0, c0;
  if (b < 384){                      // ---- Wt[m][c][q] = f16(W[m][q][c]), swizzled
    int m = b/64, rem = b%64;
    src = W.p[m]; ob = Wt + (size_t)m*256*1024;
    R = 1024; C = 256; r0 = (rem>>2)*64; c0 = (rem&3)*64;
  } else {                           // ---- Wmt[tt][e][d] = f16(Wm[tt][d][e]), swizzled
    int bb = b-384;
    int m = bb/16, rem = bb%16;
    src = Wm3.p[m]; ob = Wmt + (size_t)m*256*256;
    R = 256; C = 256; r0 = (rem>>2)*64; c0 = (rem&3)*64;
  }
  {
    const int rr = t>>4, cc = (t&15)*4;
    #pragma unroll
    for (int i=0;i<4;i++){
      float4 v = *(const float4*)(src + (size_t)(r0+rr+i*16)*C + c0 + cc);
      T_s[cc+0][rr+i*16]=f2h(v.x);
      T_s[cc+1][rr+i*16]=f2h(v.y);
      T_s[cc+2][rr+i*16]=f2h(v.z);
      T_s[cc+3][rr+i*16]=f2h(v.w);
    }
    __syncthreads();
    const int cr = t>>4, rc = (t&15)*4;
    #pragma unroll
    for (int i=0;i<4;i++){
      int c = c0 + cr + i*16;
      ushort4 v = { T_s[cr+i*16][rc+0], T_s[cr+i*16][rc+1],
                    T_s[cr+i*16][rc+2], T_s[cr+i*16][rc+3] };
      int col = (r0 + rc) ^ ((c&7)<<3);
      *(ushort4*)(ob + (size_t)c*R + col) = v;
    }
  }
}

// ------------- Kernel B: gather-max + instance attention. ONE WAVE PER (n,m), no barriers -------------
template<int P>
__device__ inline void inst_core(const AllMP& mp, int m, int n, int l,
                                 const float* __restrict__ wa_all,
                                 unsigned int (*inst_lds)[128], float (*alpha_lds)[4],
                                 unsigned short* __restrict__ ctxh){
  const int g = l >> 4;   // head group
  const int j = l & 15;   // lane in group
  const int* __restrict__ gidx = mp.idx[m] + (size_t)n*(KK*P);

  // wa for head g, this lane's 16 dims {4j+64c .. +3}
  h2 wh[8];
  {
    const float4* wab = (const float4*)(wa_all + m*1024 + g*256);
    #pragma unroll
    for (int c=0;c<4;c++){
      float4 wv = wab[j + 16*c];
      wh[2*c]   = packh2(wv.x, wv.y);
      wh[2*c+1] = packh2(wv.z, wv.w);
    }
  }

  // sg = Xt[n]·wa[g] via group reduce
  float sg;
  {
    const uint2* xb = (const uint2*)(mp.xt[m] + (size_t)n*DD);
    float p_ = 0.f;
    #pragma unroll
    for (int c=0;c<4;c++){
      uint2 rr = xb[j + 16*c];
      p_ = dot2(bch2(rr.x), wh[2*c+0], p_);
      p_ = dot2(bch2(rr.y), wh[2*c+1], p_);
    }
    sg = gsum16(p_);
  }

  // Phase 1: gather-max. Lane l owns cols 4l..4l+3; keep in regs AND mirror to LDS.
  unsigned int v0[KK], v1[KK];
  #pragma unroll
  for (int k=0;k<KK;k++){
    h2 a, bb;
    {
      int id = gidx[k*P];                     // wave-uniform -> s_load
      const uint2* rp = (const uint2*)(mp.xs[m][0] + (size_t)id*DD);
      uint2 r = rp[l];
      a = bch2(r.x); bb = bch2(r.y);
    }
    #pragma unroll
    for (int p=1;p<P;p++){
      int id = gidx[k*P+p];
      const uint2* rp = (const uint2*)(mp.xs[m][p] + (size_t)id*DD);
      uint2 u = rp[l];
      a = hmax2(a, bch2(u.x)); bb = hmax2(bb, bch2(u.y));
    }
    v0[k] = bcu(a); v1[k] = bcu(bb);
    *(uint2*)&inst_lds[k][2*l] = make_uint2(v0[k], v1[k]);
  }

  // Phase 2: logits via 16-lane-group dots (same-wave LDS RAW, no barrier)
  float e[KK];
  #pragma unroll
  for (int k=0;k<KK;k++){
    float pr = 0.f;
    #pragma unroll
    for (int c=0;c<4;c++){
      uint2 rr = *(const uint2*)&inst_lds[k][2*(j+16*c)];
      pr = dot2(bch2(rr.x), wh[2*c+0], pr);
      pr = dot2(bch2(rr.y), wh[2*c+1], pr);
    }
    pr = gsum16(pr);
    float logit = pr + sg;
    e[k] = (logit>0.f) ? logit : 0.2f*logit;
  }

  // Phase 3: softmax fully in registers (all 16 lanes of group g hold head-g logits)
  float mx = e[0];
  #pragma unroll
  for (int k=1;k<KK;k++) mx = fmaxf(mx, e[k]);
  float s = 0.f;
  #pragma unroll
  for (int k=0;k<KK;k++){ e[k] = __expf(e[k]-mx); s += e[k]; }
  float inv = 1.0f/s;
  #pragma unroll
  for (int k=0;k<KK;k++) e[k] *= inv;
  // share alphas across head groups via tiny LDS (same wave)
  if (j==0){
    #pragma unroll
    for (int k=0;k<KK;k++) alpha_lds[k][g] = e[k];
  }

  // Phase 4: ctx from REGISTER copy of inst; fp32 accumulate
  float c[4][4] = {};
  #pragma unroll
  for (int k=0;k<KK;k++){
    float4 af = *(const float4*)&alpha_lds[k][0];   // broadcast
    h2 x0 = bch2(v0[k]), x1 = bch2(v1[k]);
    float f0=(float)x0[0], f1=(float)x0[1], f2=(float)x1[0], f3=(float)x1[1];
    c[0][0]+=af.x*f0; c[0][1]+=af.x*f1; c[0][2]+=af.x*f2; c[0][3]+=af.x*f3;
    c[1][0]+=af.y*f0; c[1][1]+=af.y*f1; c[1][2]+=af.y*f2; c[1][3]+=af.y*f3;
    c[2][0]+=af.z*f0; c[2][1]+=af.z*f1; c[2][2]+=af.z*f2; c[2][3]+=af.z*f3;
    c[3][0]+=af.w*f0; c[3][1]+=af.w*f1; c[3][2]+=af.w*f2; c[3][3]+=af.w*f3;
  }

  // store pre-swizzled fp16 ctx
  unsigned short* cb = ctxh + ((size_t)m*NN + n)*1024;
  const int col = (4*l) ^ ((n&7)<<3);
  #pragma unroll
  for (int h=0;h<4;h++){
    ushort4 o = { f2h(c[h][0]), f2h(c[h][1]), f2h(c[h][2]), f2h(c[h][3]) };
    *(ushort4*)(cb + h*DD + col) = o;
  }
}

__launch_bounds__(64)
__global__ void inst_attn_kernel(AllMP mp, const float* __restrict__ wa_all,
                                 unsigned short* __restrict__ ctxh){
  __shared__ unsigned int inst_lds[KK][128];   // 10 KB, packed fp16
  __shared__ float alpha_lds[KK][4];           // 320 B
  const int m = blockIdx.y;
  const int n = blockIdx.x;
  const int l = threadIdx.x;                   // one wave
  switch(mp.P[m]){
    case 3: inst_core<3>(mp,m,n,l,wa_all,inst_lds,alpha_lds,ctxh); break;
    case 4: inst_core<4>(mp,m,n,l,wa_all,inst_lds,alpha_lds,ctxh); break;
    default: inst_core<5>(mp,m,n,l,wa_all,inst_lds,alpha_lds,ctxh); break;
  }
}

// ---------- Kernel C: Hmp[m] = (1/H) * ctx_f16 @ W_f16 (MFMA, dbuf glds, 1 barrier/iter) ----------
__launch_bounds__(256)
__global__ void gemm_kernel(const unsigned short* __restrict__ ctxh,
                            const unsigned short* __restrict__ Wt,
                            unsigned short* __restrict__ Hmp){
  __shared__ unsigned short A_s[2][64][64];
  __shared__ unsigned short B_s[2][64][64];
  const int m  = blockIdx.z;
  const int n0 = blockIdx.x*64, c0 = blockIdx.y*64;
  const int t  = threadIdx.x;
  const int l  = t & 63;
  const int wid  = t >> 6;
  const int wrow = wid & 1, wcol = wid >> 1;
  const unsigned short* Abase = ctxh + (size_t)m*NN*1024;
  const unsigned short* Bbase = Wt   + (size_t)m*256*1024;

  f32x4 acc[2][2] = {};
  const int row8 = l>>3, seg = l&7;

  // prologue stage
  {
    #pragma unroll
    for (int i=0;i<2;i++){
      const int r = wid*16 + i*8;
      glds16(Abase + (size_t)(n0+r+row8)*1024 + 0 + seg*8, &A_s[0][r][0]);
      glds16(Bbase + (size_t)(c0+r+row8)*1024 + 0 + seg*8, &B_s[0][r][0]);
    }
  }
  __syncthreads();

  #pragma unroll 2
  for (int it=0; it<16; it++){
    const int buf = it&1;
    if (it<15){
      const int k0 = (it+1)*64;
      #pragma unroll
      for (int i=0;i<2;i++){
        const int r = wid*16 + i*8;
        glds16(Abase + (size_t)(n0+r+row8)*1024 + k0 + seg*8, &A_s[buf^1][r][0]);
        glds16(Bbase + (size_t)(c0+r+row8)*1024 + k0 + seg*8, &B_s[buf^1][r][0]);
      }
    }
    __builtin_amdgcn_s_setprio(1);
    #pragma unroll
    for (int kf=0;kf<2;kf++){
      half8 a[2], b[2];
      const int s = kf*4 + (l>>4);
      #pragma unroll
      for (int mr=0;mr<2;mr++){
        const int row = wrow*32 + mr*16 + (l&15);
        a[mr] = __builtin_bit_cast(half8, *(const short8*)&A_s[buf][row][(s ^ (row&7))*8]);
      }
      #pragma unroll
      for (int nr=0;nr<2;nr++){
        const int col = wcol*32 + nr*16 + (l&15);
        b[nr] = __builtin_bit_cast(half8, *(const short8*)&B_s[buf][col][(s ^ (col&7))*8]);
      }
      #pragma unroll
      for (int mr=0;mr<2;mr++)
        #pragma unroll
        for (int nr=0;nr<2;nr++)
          acc[mr][nr] = __builtin_amdgcn_mfma_f32_16x16x32_f16(a[mr], b[nr], acc[mr][nr], 0,0,0);
    }
    __builtin_amdgcn_s_setprio(0);
    __syncthreads();   // drains vmcnt+lgkm, gates buf swap
  }

  unsigned short* out = Hmp + (size_t)m*NN*DD;
  #pragma unroll
  for (int mr=0;mr<2;mr++){
    const int rbase = n0 + wrow*32 + mr*16 + (l>>4)*4;
    #pragma unroll
    for (int nr=0;nr<2;nr++){
      const int col = c0 + wcol*32 + nr*16 + (l&15);
      #pragma unroll
      for (int r=0;r<4;r++){
        const int rw = rbase + r;
        out[(size_t)rw*DD + (col ^ ((rw&7)<<3))] = f2h(acc[mr][nr][r]*0.25f);
      }
    }
  }
}

// ------- Kernel E (MFMA): sem_sum[m,e] += sum_n tanh(Hmp[m,n,:]·Wm[:,e] + bm[e]) -------
__launch_bounds__(256)
__global__ void sem_kernel(const unsigned short* __restrict__ Hmp, SemB sb,
                           float* __restrict__ sem_sum){
  __shared__ unsigned short A_s[64][256];
  __shared__ unsigned short B_s[64][256];
  const int m  = blockIdx.z;
  const int n0 = blockIdx.x*64, c0 = blockIdx.y*64;
  const int t  = threadIdx.x, l = t & 63, wid = t >> 6;
  const int wrow = wid & 1, wcol = wid >> 1;
  const unsigned short* Ab = Hmp + (size_t)m*NN*DD;
  const unsigned short* Bb = sb.Wmt[m];

  const int row2 = l>>5, seg = l&31;
  #pragma unroll
  for (int i=0;i<8;i++){
    const int r = wid*16 + i*2;
    glds16(Ab + (size_t)(n0+r+row2)*DD + seg*8, &A_s[r][0]);
    glds16(Bb + (size_t)(c0+r+row2)*DD + seg*8, &B_s[r][0]);
  }
  __syncthreads();

  f32x4 acc[2][2] = {};
  #pragma unroll
  for (int kf=0; kf<8; kf++){
    const int s = kf*4 + (l>>4);
    half8 a[2], b[2];
    #pragma unroll
    for (int mr=0;mr<2;mr++){
      int row = wrow*32 + mr*16 + (l&15);
      int ss = (s&24) | ((s&7)^(row&7));
      a[mr] = __builtin_bit_cast(half8, *(const short8*)((const char*)&A_s[0][0] + row*512 + ss*16));
    }
    #pragma unroll
    for (int nr=0;nr<2;nr++){
      int row = wcol*32 + nr*16 + (l&15);
      int ss = (s&24) | ((s&7)^(row&7));
      b[nr] = __builtin_bit_cast(half8, *(const short8*)((const char*)&B_s[0][0] + row*512 + ss*16));
    }
    #pragma unroll
    for (int mr=0;mr<2;mr++)
      #pragma unroll
      for (int nr=0;nr<2;nr++)
        acc[mr][nr] = __builtin_amdgcn_mfma_f32_16x16x32_f16(a[mr], b[nr], acc[mr][nr], 0,0,0);
  }

  #pragma unroll
  for (int nr=0;nr<2;nr++){
    const int col = c0 + wcol*32 + nr*16 + (l&15);
    float b = sb.bm[m][col];
    float sv = 0.f;
    #pragma unroll
    for (int mr=0;mr<2;mr++)
      #pragma unroll
      for (int r=0;r<4;r++)
        sv += tanhf(acc[mr][nr][r] + b);
    sv += __shfl_xor(sv,16);
    sv += __shfl_xor(sv,32);
    if (l < 16) atomicAdd(&sem_sum[m*DD + col], sv);
  }
}

// ------- Kernel G (fused beta+combine): per block compute beta, then 4 rows of output -------
__launch_bounds__(256)
__global__ void combine_kernel(const unsigned short* __restrict__ Hmp,
                               const float* __restrict__ sem_sum,
                               const float* __restrict__ qm0, const float* __restrict__ qm1,
                               const float* __restrict__ qm2,
                               float* __restrict__ out){
  const int type = blockIdx.y;
  const int start = (type==0) ? 0 : (type==1) ? 2 : 5;
  const int P = (type==0) ? 2 : (type==1) ? 3 : 1;
  const float* qm = (type==0) ? qm0 : (type==1) ? qm1 : qm2;
  const int t = threadIdx.x;
  __shared__ float red[3][4];
  __shared__ float beta_s[3];

  float q = qm[t];
  #pragma unroll
  for (int p=0;p<3;p++){
    if (p < P){
      float sm = sem_sum[(start+p)*DD + t] * (1.0f/NN);
      float v = wsum(tanhf(sm)*q);
      if ((t&63)==0) red[p][t>>6] = v;
    }
  }
  __syncthreads();
  if (t==0){
    float logits[3], e[3];
    float mx = -INFINITY;
    #pragma unroll
    for (int p=0;p<3;p++){
      if (p < P){
        logits[p] = red[p][0]+red[p][1]+red[p][2]+red[p][3];
        mx = fmaxf(mx, logits[p]);
      }
    }
    float s = 0.f;
    #pragma unroll
    for (int p=0;p<3;p++){
      if (p < P){ e[p] = __expf(logits[p]-mx); s += e[p]; }
    }
    #pragma unroll
    for (int p=0;p<3;p++)
      if (p < P) beta_s[p] = e[p]/s;
  }
  __syncthreads();

  if (blockIdx.x==0 && t<P)
    out[(size_t)3*NN*DD + start + t] = beta_s[t];

  const int n0 = blockIdx.x*4;
  #pragma unroll
  for (int r=0;r<4;r++){
    const int n = n0 + r;
    const int ds = t ^ ((n&7)<<3);
    const unsigned short* base = Hmp + ((size_t)start*NN + n)*DD + ds;
    float acc = 0.f;
    #pragma unroll
    for (int p=0;p<3;p++)
      if (p < P) acc += beta_s[p]*h2f(base[(size_t)p*NN*DD]);
    out[((size_t)type*NN + n)*DD + t] = acc;
  }
}

extern "C" void kernel_launch(void* const* d_in, const int* in_sizes, int n_in,
                              void* d_out, int out_size, void* d_ws, size_t ws_size,
                              hipStream_t stream) {
  SixPtr Xp; Xp.p[0]=(const float*)d_in[0]; Xp.p[1]=(const float*)d_in[1]; Xp.p[2]=(const float*)d_in[2];
  for (int i=3;i<6;i++) Xp.p[i]=Xp.p[0];

  SixPtr Wl, al;
  for (int m=0;m<6;m++){ Wl.p[m] = (const float*)d_in[9+2*m]; al.p[m] = (const float*)d_in[10+2*m]; }
  const float* Wm_[3]; const float* bm_[3]; const float* qm_[3];
  for (int tt=0;tt<3;tt++){
    Wm_[tt] = (const float*)d_in[21+3*tt];
    bm_[tt] = (const float*)d_in[22+3*tt];
    qm_[tt] = (const float*)d_in[23+3*tt];
  }
  SixPtr Wm3; for (int i=0;i<6;i++) Wm3.p[i] = Wm_[i<3?i:0];

  // ---- workspace layout (~46 MB; ws_size = 256 MiB per round-4 poison fill) ----
  char* ws = (char*)d_ws;
  float* wa_all  = (float*)ws;                               ws += 6*1024*4;
  float* sem_sum = (float*)ws;                               ws += 6*DD*4;
  unsigned short* Hmp  = (unsigned short*)ws;                ws += (size_t)6*NN*DD*2;
  unsigned short* Wt   = (unsigned short*)ws;                ws += (size_t)6*256*1024*2;
  unsigned short* Wmt  = (unsigned short*)ws;                ws += (size_t)3*256*256*2;
  unsigned short* Xh   = (unsigned short*)ws;                ws += (size_t)3*NN*DD*2;
  unsigned short* ctxh = (unsigned short*)ws;                // 6*NN*1024*2 = 24 MB

  AllMP mp;
  for (int m=0;m<6;m++) mp.idx[m] = (const int*)d_in[3+m];
  const int P_[6] = {3,5,3,3,4,5};
  for (int m=0;m<6;m++) mp.P[m] = P_[m];
  const int xt_t[6] = {0,0,1,1,1,2};
  const int gp_t[6][5] = {
    {0,1,0,0,0}, {0,1,2,1,0}, {1,2,1,1,1},
    {1,0,1,1,1}, {1,0,0,1,1}, {2,1,0,1,2}};
  for (int m=0;m<6;m++){
    mp.xt[m] = Xh + (size_t)xt_t[m]*NN*DD;
    for (int p=0;p<5;p++) mp.xs[m][p] = Xh + (size_t)gp_t[m][p]*NN*DD;
  }

  SemB sb;
  const int type_of[6] = {0,0,1,1,1,2};
  for (int m=0;m<6;m++){
    sb.Wmt[m] = Wmt + (size_t)type_of[m]*256*256;
    sb.bm[m]  = bm_[type_of[m]];
  }

  prep_kernel<<<dim3(24+1536+384+48),dim3(256),0,stream>>>(
      Wl, al, Xp, Wm3, wa_all, Xh, Wt, Wmt, sem_sum, 6*DD);

  inst_attn_kernel<<<dim3(NN,6),dim3(64),0,stream>>>(mp, wa_all, ctxh);
  gemm_kernel<<<dim3(32,4,6),dim3(256),0,stream>>>(ctxh, Wt, Hmp);
  sem_kernel<<<dim3(32,4,6),dim3(256),0,stream>>>(Hmp, sb, sem_sum);

  float* out = (float*)d_out;
  combine_kernel<<<dim3(NN/4,3),dim3(256),0,stream>>>(Hmp, sem_sum, qm_[0], qm_[1], qm_[2], out);
}